// Round 10
// baseline (98.865 us; speedup 1.0000x reference)
//
#include <hip/hip_runtime.h>
#include <hip/hip_bf16.h>

#define Bn 16
#define Cn 2048
#define Qn 128
#define En 200
#define Fn 800
#define On 128
#define EP 208   // padded e-rows for xcT
#define KP 224   // padded e-dim for k_tail slots (7 x K32)
#define XR 448   // xqaT rows: [0,224) xq^T (+pad), [224,448) a^T (+pad)
#define CP 232   // LDS pitch for xbuf/cbuf (2-way bank)

typedef float f32x4 __attribute__((ext_vector_type(4)));
typedef __bf16 bf16x8 __attribute__((ext_vector_type(8)));

__device__ __forceinline__ unsigned short f2bf(float f) {
    union { float f; unsigned u; } v; v.f = f;
    unsigned r = v.u + 0x7FFF + ((v.u >> 16) & 1);
    return (unsigned short)(r >> 16);
}
__device__ __forceinline__ float bf2f(unsigned short h) {
    union { unsigned u; float f; } v; v.u = (unsigned)h << 16;
    return v.f;
}
__device__ __forceinline__ bf16x8 mul8(bf16x8 a, bf16x8 b) {
    bf16x8 o;
#pragma unroll
    for (int k = 0; k < 8; ++k) o[k] = (__bf16)((float)a[k] * (float)b[k]);
    return o;
}
__device__ __forceinline__ bf16x8 scale8(bf16x8 a, float s) {
    bf16x8 o;
#pragma unroll
    for (int k = 0; k < 8; ++k) o[k] = (__bf16)((float)a[k] * s);
    return o;
}

// ---- k_prep_all: {yq+s_q | wpP | xq^T+pads | xc->bf16+xc^T} ---------------
__global__ __launch_bounds__(256) void k_prep_all(const float* __restrict__ xq,
                                                  const float* __restrict__ wsim,
                                                  const float* __restrict__ wp,
                                                  const float* __restrict__ xc,
                                                  unsigned short* __restrict__ yqb,
                                                  float* __restrict__ s_q,
                                                  unsigned short* __restrict__ wpP,
                                                  unsigned short* __restrict__ xqaT,
                                                  unsigned short* __restrict__ xcb,
                                                  unsigned short* __restrict__ xcT) {
    int bx = blockIdx.x;
    if (bx < 512) {
        int wid = (bx * 256 + threadIdx.x) >> 6;
        int lane = threadIdx.x & 63;
        const float* xrow = xq + (size_t)wid * En;
        float s = 0.f;
        for (int e = lane; e < En; e += 64) {
            float x = xrow[e];
            yqb[(size_t)wid * En + e] = f2bf(x * wsim[400 + e] + wsim[e]);
            s += x * wsim[200 + e];
        }
        for (int i = 32; i; i >>= 1) s += __shfl_xor(s, i, 64);
        if (lane == 0) s_q[wid] = s;
    } else if (bx < 624) {
        // wpP[s][o][k] = wp[o][s*200+k] (k<200) else 0 ; 112 blocks
        int gid = (bx - 512) * 256 + threadIdx.x;
        int flat = gid * 4;                       // < 4*128*224 = 114688
        int s = flat / (On * KP);
        int rem = flat % (On * KP);
        int o = rem / KP, k = rem % KP;
        ushort4 ov = {0, 0, 0, 0};
        if (k < 200) {
            float4 v = *(const float4*)(wp + (size_t)o * Fn + s * 200 + k);
            ov.x = f2bf(v.x); ov.y = f2bf(v.y); ov.z = f2bf(v.z); ov.w = f2bf(v.w);
        }
        *(ushort4*)(wpP + flat) = ov;
    } else if (bx < 752) {
        // xqaT rows [0,200) = xq^T ; zero pads [200,224) & [424,448)
        int lb = bx - 624;                 // 128 blocks: (4 et, 2 qt, 16 b)
        int et = lb & 3, qt = (lb >> 2) & 1, b = lb >> 3;
        int e0 = et * 64, q0 = qt * 64;
        int tid = threadIdx.x;
        __shared__ float t[64][65];
        for (int i = tid; i < 64 * 64; i += 256) {
            int qi = i >> 6, ei = i & 63;
            int e = e0 + ei;
            t[qi][ei] = (e < En) ? xq[((size_t)(b * Qn + q0 + qi)) * En + e] : 0.f;
        }
        __syncthreads();
        for (int i = tid; i < 64 * 64; i += 256) {
            int ei = i >> 6, qi = i & 63;
            int e = e0 + ei;
            if (e < En)
                xqaT[((size_t)(b * XR + e)) * Qn + q0 + qi] = f2bf(t[qi][ei]);
        }
        if (et == 3) {
            for (int i = tid; i < 24 * 64; i += 256) {
                int e = 200 + (i >> 6), q = q0 + (i & 63);
                xqaT[((size_t)(b * XR + e)) * Qn + q] = 0;
            }
            for (int i = tid; i < 24 * 64; i += 256) {
                int e = 424 + (i >> 6), q = q0 + (i & 63);
                xqaT[((size_t)(b * XR + e)) * Qn + q] = 0;
            }
        }
    } else {
        int lb = bx - 752;                 // 2048 blocks: (32 ct, 4 et, 16 b)
        int ct = lb & 31, et = (lb >> 5) & 3, b = lb >> 7;
        int c0 = ct * 64, e0 = et * 64;
        int tid = threadIdx.x;
        __shared__ float t[64][65];
        for (int i = tid; i < 64 * 64; i += 256) {
            int ci = i >> 6, ei = i & 63;
            int e = e0 + ei;
            t[ci][ei] = (e < En) ? xc[((size_t)(b * Cn + c0 + ci)) * En + e] : 0.f;
        }
        __syncthreads();
        for (int i = tid; i < 64 * 16; i += 256) {
            int ci = i >> 4, g4 = (i & 15) * 4;
            int e = e0 + g4;
            if (e + 3 < En) {
                ushort4 o;
                o.x = f2bf(t[ci][g4]); o.y = f2bf(t[ci][g4 + 1]);
                o.z = f2bf(t[ci][g4 + 2]); o.w = f2bf(t[ci][g4 + 3]);
                *(ushort4*)(xcb + ((size_t)(b * Cn + c0 + ci)) * En + e) = o;
            }
        }
        for (int i = tid; i < 64 * 64; i += 256) {
            int ei = i >> 6, ci = i & 63;
            int e = e0 + ei;
            if (e < EP)
                xcT[((size_t)(b * EP + e)) * Cn + c0 + ci] = f2bf(t[ci][ei]);
        }
    }
}

// ---- k_scores_mfma: scores GEMM + fused row softmax (s1) + block-local ----
__global__ __launch_bounds__(256) void k_scores_mfma(const unsigned short* __restrict__ xcb,
                                                     const unsigned short* __restrict__ yqb,
                                                     const float* __restrict__ s_q,
                                                     unsigned short* __restrict__ ET,
                                                     unsigned short* __restrict__ s1,
                                                     float* __restrict__ cpM,
                                                     float* __restrict__ cpS) {
    int b = blockIdx.y, blk = blockIdx.x, c0 = blk * 64;
    int w = threadIdx.x >> 6, lane = threadIdx.x & 63;
    int lrow = lane & 15, kg = lane >> 4;
    __shared__ float colm4[4][128];
    __shared__ float cols4[4][128];
    const unsigned short* Ab = xcb + ((size_t)(b * Cn + c0 + w * 16 + lrow)) * En + kg * 8;
    const unsigned short* Bb = yqb + ((size_t)(b * Qn + lrow)) * En + kg * 8;
    f32x4 acc[8] = {};
#pragma unroll
    for (int kc = 0; kc < 7; ++kc) {
        bool valid = (kc < 6) || (kg == 0);
        bf16x8 af = bf16x8{0,0,0,0,0,0,0,0};
        if (valid) af = *(const bf16x8*)(Ab + kc * 32);
        bf16x8 bfr[8];
#pragma unroll
        for (int j = 0; j < 8; ++j) {
            bfr[j] = bf16x8{0,0,0,0,0,0,0,0};
            if (valid) bfr[j] = *(const bf16x8*)(Bb + (size_t)j * 16 * En + kc * 32);
        }
#pragma unroll
        for (int j = 0; j < 8; ++j)
            acc[j] = __builtin_amdgcn_mfma_f32_16x16x32_bf16(af, bfr[j], acc[j], 0, 0, 0);
    }
#pragma unroll
    for (int j = 0; j < 8; ++j) {
        float sq = s_q[b * Qn + j * 16 + lrow];
#pragma unroll
        for (int r = 0; r < 4; ++r) acc[j][r] += sq;
    }
    float lm[8], ls[8];
#pragma unroll
    for (int j = 0; j < 8; ++j) {
        float m = fmaxf(fmaxf(acc[j][0], acc[j][1]), fmaxf(acc[j][2], acc[j][3]));
        m = fmaxf(m, __shfl_xor(m, 16, 64));
        m = fmaxf(m, __shfl_xor(m, 32, 64));
        lm[j] = m;
        float s = __expf(acc[j][0] - m) + __expf(acc[j][1] - m)
                + __expf(acc[j][2] - m) + __expf(acc[j][3] - m);
        s += __shfl_xor(s, 16, 64);
        s += __shfl_xor(s, 32, 64);
        ls[j] = s;
    }
    if (kg == 0) {
#pragma unroll
        for (int j = 0; j < 8; ++j) {
            colm4[w][j * 16 + lrow] = lm[j];
            cols4[w][j * 16 + lrow] = ls[j];
        }
    }
    __syncthreads();
    float mb[8];
#pragma unroll
    for (int j = 0; j < 8; ++j) {
        int q = j * 16 + lrow;
        float m = fmaxf(fmaxf(colm4[0][q], colm4[1][q]), fmaxf(colm4[2][q], colm4[3][q]));
        mb[j] = m;
        if (w == 0 && kg == 0) {
            float sb = cols4[0][q] * __expf(colm4[0][q] - m)
                     + cols4[1][q] * __expf(colm4[1][q] - m)
                     + cols4[2][q] * __expf(colm4[2][q] - m)
                     + cols4[3][q] * __expf(colm4[3][q] - m);
            cpM[(b * 32 + blk) * 128 + q] = m;
            cpS[(b * 32 + blk) * 128 + q] = sb;
        }
    }
#pragma unroll
    for (int j = 0; j < 8; ++j) {
        int q = j * 16 + lrow;
        ushort4 o;
        o.x = f2bf(__expf(acc[j][0] - mb[j]));
        o.y = f2bf(__expf(acc[j][1] - mb[j]));
        o.z = f2bf(__expf(acc[j][2] - mb[j]));
        o.w = f2bf(__expf(acc[j][3] - mb[j]));
        *(ushort4*)(ET + ((size_t)(b * Qn + q)) * Cn + c0 + w * 16 + kg * 4) = o;
    }
    size_t rowbase = (size_t)(b * Cn + c0 + w * 16 + kg * 4);
#pragma unroll
    for (int r = 0; r < 4; ++r) {
        float m = acc[0][r];
#pragma unroll
        for (int j = 1; j < 8; ++j) m = fmaxf(m, acc[j][r]);
        for (int d = 1; d < 16; d <<= 1) m = fmaxf(m, __shfl_xor(m, d, 64));
        float ssum = 0.f;
        float e[8];
#pragma unroll
        for (int j = 0; j < 8; ++j) {
            e[j] = __expf(acc[j][r] - m);
            ssum += e[j];
        }
        for (int d = 1; d < 16; d <<= 1) ssum += __shfl_xor(ssum, d, 64);
        float si = 1.f / ssum;
#pragma unroll
        for (int j = 0; j < 8; ++j)
            s1[(rowbase + r) * Qn + j * 16 + lrow] = f2bf(e[j] * si);
    }
}

// ---- k_a_part: a^T partials = xcT @ (ET*corr)^T; colcomb+corr fused -------
__global__ __launch_bounds__(256) void k_a_part(const unsigned short* __restrict__ ET,
                                                const unsigned short* __restrict__ xcT,
                                                const float* __restrict__ cpM,
                                                const float* __restrict__ cpS,
                                                float* __restrict__ aP) {
    int mt = blockIdx.x, ks = blockIdx.y, b = blockIdx.z;
    int tid = threadIdx.x;
    int w = tid >> 6, lane = tid & 63;
    int lrow = lane & 15, kg = lane >> 4;
    __shared__ float colMs[128], colSis[128];
    if (tid < 128) {
        int q = tid;
        float m = -1e30f;
        for (int k = 0; k < 32; k++) m = fmaxf(m, cpM[(b * 32 + k) * 128 + q]);
        float s = 0.f;
        for (int k = 0; k < 32; k++) s += cpS[(b * 32 + k) * 128 + q] * __expf(cpM[(b * 32 + k) * 128 + q] - m);
        colMs[q] = m;
        colSis[q] = 1.f / s;
    }
    __syncthreads();
    int q0 = w * 16 + lrow, q1 = q0 + 64;
    int cb0 = ks * 8;
    float corr0[8], corr1[8];
#pragma unroll
    for (int i = 0; i < 8; ++i) {
        corr0[i] = __expf(cpM[(b * 32 + cb0 + i) * 128 + q0] - colMs[q0]) * colSis[q0];
        corr1[i] = __expf(cpM[(b * 32 + cb0 + i) * 128 + q1] - colMs[q1]) * colSis[q1];
    }
    const unsigned short* Ab = xcT + ((size_t)(b * EP + mt * 16 + lrow)) * Cn + ks * 512 + kg * 8;
    const unsigned short* B0 = ET + ((size_t)(b * Qn + q0)) * Cn + ks * 512 + kg * 8;
    const unsigned short* B1 = ET + ((size_t)(b * Qn + q1)) * Cn + ks * 512 + kg * 8;
    f32x4 acc0 = {}, acc1 = {};
#pragma unroll
    for (int kb = 0; kb < 4; ++kb) {
        bf16x8 af[4], bv0[4], bv1[4];
#pragma unroll
        for (int k4 = 0; k4 < 4; ++k4) {
            af[k4]  = *(const bf16x8*)(Ab + (kb * 4 + k4) * 32);
            bv0[k4] = *(const bf16x8*)(B0 + (kb * 4 + k4) * 32);
            bv1[k4] = *(const bf16x8*)(B1 + (kb * 4 + k4) * 32);
        }
#pragma unroll
        for (int k4 = 0; k4 < 4; ++k4) {
            bf16x8 s0 = scale8(bv0[k4], corr0[kb * 2 + (k4 >> 1)]);
            bf16x8 s1v = scale8(bv1[k4], corr1[kb * 2 + (k4 >> 1)]);
            acc0 = __builtin_amdgcn_mfma_f32_16x16x32_bf16(af[k4], s0, acc0, 0, 0, 0);
            acc1 = __builtin_amdgcn_mfma_f32_16x16x32_bf16(af[k4], s1v, acc1, 0, 0, 0);
        }
    }
    size_t ebase = (size_t)(b * 4 + ks) * EP + mt * 16 + kg * 4;
#pragma unroll
    for (int r = 0; r < 4; ++r) {
        aP[(ebase + r) * Qn + q0] = acc0[r];
        aP[(ebase + r) * Qn + q1] = acc1[r];
    }
}

// ---- k_acomb2: sum 4 partials -> xqaT rows [224,424) ----------------------
__global__ void k_acomb2(const float* __restrict__ aP, unsigned short* __restrict__ xqaT) {
    int gid = blockIdx.x * 256 + threadIdx.x;
    if (gid >= Bn * En * Qn) return;
    int b = gid / (En * Qn), r = gid % (En * Qn);
    int e = r / Qn, q = r % Qn;
    float s = 0.f;
#pragma unroll
    for (int k = 0; k < 4; k++)
        s += aP[((size_t)(b * 4 + k) * EP + e) * Qn + q];
    xqaT[((size_t)(b * XR + 224 + e)) * Qn + q] = f2bf(s);
}

// ---- ph1 helper: NJ n-tiles x 4 m-tiles of s1t @ xrows -> cbuf ------------
template<int NJ>
__device__ __forceinline__ void cq2(const unsigned short* __restrict__ s1t,
                                    const unsigned short* __restrict__ xrows,
                                    unsigned short* __restrict__ cbuf,
                                    int J0, int kg, int lrow) {
    f32x4 acc[NJ][4];
#pragma unroll
    for (int j = 0; j < NJ; ++j)
#pragma unroll
        for (int m = 0; m < 4; ++m) acc[j][m] = f32x4{0.f, 0.f, 0.f, 0.f};
#pragma unroll
    for (int kc = 0; kc < 4; ++kc) {
        bf16x8 a[4];
#pragma unroll
        for (int m = 0; m < 4; ++m)
            a[m] = *(const bf16x8*)(s1t + (m * 16 + lrow) * 136 + kg * 8 + kc * 32);
        bf16x8 bv[NJ];
#pragma unroll
        for (int j = 0; j < NJ; ++j)
            bv[j] = *(const bf16x8*)(xrows + ((size_t)((J0 + j) * 16 + lrow)) * Qn + kg * 8 + kc * 32);
#pragma unroll
        for (int j = 0; j < NJ; ++j)
#pragma unroll
            for (int m = 0; m < 4; ++m)
                acc[j][m] = __builtin_amdgcn_mfma_f32_16x16x32_bf16(a[m], bv[j], acc[j][m], 0, 0, 0);
    }
#pragma unroll
    for (int j = 0; j < NJ; ++j) {
        int col = (J0 + j) * 16 + lrow;
#pragma unroll
        for (int m = 0; m < 4; ++m)
#pragma unroll
            for (int r = 0; r < 4; ++r)
                cbuf[(m * 16 + kg * 4 + r) * CP + col] = f2bf(acc[j][m][r]);
    }
}

// ---- k_tail: slot-phased fusion, 64-row tiles, 75 KB LDS -> 2 blocks/CU ---
// out = x@wp0 + c2q@wp1 + (x*c2q)@wp2 + (x*q2c)@wp3 ; c2q/q2c share cbuf
__global__ __launch_bounds__(512, 4) void k_tail(const unsigned short* __restrict__ s1,
                                                 const unsigned short* __restrict__ xqaT,
                                                 const unsigned short* __restrict__ xcb,
                                                 const unsigned short* __restrict__ wpP,
                                                 const float* __restrict__ bp,
                                                 float* __restrict__ out) {
    int b = blockIdx.y, c0 = blockIdx.x * 64;
    int tid = threadIdx.x;
    int w = tid >> 6, lane = tid & 63;
    int lrow = lane & 15, kg = lane >> 4;
    __shared__ unsigned short s1t[64 * 136];   // 17.4 KB
    __shared__ unsigned short xbuf[64 * CP];   // 29.7 KB
    __shared__ unsigned short cbuf[64 * CP];   // 29.7 KB

    for (int i = tid; i < 64 * 16; i += 512) {
        int row = i >> 4, c8 = i & 15;
        *(bf16x8*)(s1t + row * 136 + c8 * 8) =
            *(const bf16x8*)(s1 + ((size_t)(b * Cn + c0 + row)) * Qn + c8 * 8);
    }
    for (int i = tid; i < 64 * 28; i += 512) {   // 25 data chunks + 3 zero-pad
        int row = i / 28, c8 = i % 28;
        bf16x8 v = bf16x8{0,0,0,0,0,0,0,0};
        if (c8 < 25) v = *(const bf16x8*)(xcb + ((size_t)(b * Cn + c0 + row)) * En + c8 * 8);
        *(bf16x8*)(xbuf + row * CP + c8 * 8) = v;
    }
    __syncthreads();

    f32x4 acc[4] = {};
    const unsigned short* xq_b = xqaT + (size_t)b * XR * Qn;

    // ph1a: c2q -> cbuf (14 n-tiles over 8 waves)
    if (w < 6)      cq2<2>(s1t, xq_b, cbuf, 2 * w, kg, lrow);
    else if (w == 6) cq2<1>(s1t, xq_b, cbuf, 12, kg, lrow);
    else             cq2<1>(s1t, xq_b, cbuf, 13, kg, lrow);

    // ph2a: acc += x @ wp0
    {
        const unsigned short* B0 = wpP + ((size_t)(0 * On + w * 16 + lrow)) * KP + kg * 8;
        const unsigned short* A0 = xbuf + lrow * CP + kg * 8;
#pragma unroll
        for (int kc = 0; kc < 7; ++kc) {
            bf16x8 b0 = *(const bf16x8*)(B0 + kc * 32);
#pragma unroll
            for (int m = 0; m < 4; ++m) {
                bf16x8 af = *(const bf16x8*)(A0 + m * 16 * CP + kc * 32);
                acc[m] = __builtin_amdgcn_mfma_f32_16x16x32_bf16(af, b0, acc[m], 0, 0, 0);
            }
        }
    }
    __syncthreads();

    // ph2b: acc += c2q @ wp1 + (x*c2q) @ wp2
    {
        const unsigned short* B1 = wpP + ((size_t)(1 * On + w * 16 + lrow)) * KP + kg * 8;
        const unsigned short* B2 = wpP + ((size_t)(2 * On + w * 16 + lrow)) * KP + kg * 8;
        const unsigned short* Ax = xbuf + lrow * CP + kg * 8;
        const unsigned short* Ac = cbuf + lrow * CP + kg * 8;
#pragma unroll
        for (int kc = 0; kc < 7; ++kc) {
            bf16x8 b1 = *(const bf16x8*)(B1 + kc * 32);
            bf16x8 b2 = *(const bf16x8*)(B2 + kc * 32);
#pragma unroll
            for (int m = 0; m < 4; ++m) {
                bf16x8 ac = *(const bf16x8*)(Ac + m * 16 * CP + kc * 32);
                bf16x8 ax = *(const bf16x8*)(Ax + m * 16 * CP + kc * 32);
                acc[m] = __builtin_amdgcn_mfma_f32_16x16x32_bf16(ac, b1, acc[m], 0, 0, 0);
                acc[m] = __builtin_amdgcn_mfma_f32_16x16x32_bf16(mul8(ax, ac), b2, acc[m], 0, 0, 0);
            }
        }
    }
    __syncthreads();

    // ph1b: q2c -> cbuf (xqaT rows [224,448))
    if (w < 6)      cq2<2>(s1t, xq_b + (size_t)224 * Qn, cbuf, 2 * w, kg, lrow);
    else if (w == 6) cq2<1>(s1t, xq_b + (size_t)224 * Qn, cbuf, 12, kg, lrow);
    else             cq2<1>(s1t, xq_b + (size_t)224 * Qn, cbuf, 13, kg, lrow);
    __syncthreads();

    // ph2c: acc += (x*q2c) @ wp3
    {
        const unsigned short* B3 = wpP + ((size_t)(3 * On + w * 16 + lrow)) * KP + kg * 8;
        const unsigned short* Ax = xbuf + lrow * CP + kg * 8;
        const unsigned short* Ac = cbuf + lrow * CP + kg * 8;
#pragma unroll
        for (int kc = 0; kc < 7; ++kc) {
            bf16x8 b3 = *(const bf16x8*)(B3 + kc * 32);
#pragma unroll
            for (int m = 0; m < 4; ++m) {
                bf16x8 ac = *(const bf16x8*)(Ac + m * 16 * CP + kc * 32);
                bf16x8 ax = *(const bf16x8*)(Ax + m * 16 * CP + kc * 32);
                acc[m] = __builtin_amdgcn_mfma_f32_16x16x32_bf16(mul8(ax, ac), b3, acc[m], 0, 0, 0);
            }
        }
    }

    int o = w * 16 + lrow;
    float bpv = bp[o];
#pragma unroll
    for (int m = 0; m < 4; ++m)
#pragma unroll
        for (int r = 0; r < 4; ++r)
            out[((size_t)(b * Cn + c0 + m * 16 + kg * 4 + r)) * On + o] = acc[m][r] + bpv;
}

extern "C" void kernel_launch(void* const* d_in, const int* in_sizes, int n_in,
                              void* d_out, int out_size, void* d_ws, size_t ws_size,
                              hipStream_t stream) {
    const float* xc = (const float*)d_in[0];
    const float* xq = (const float*)d_in[1];
    const float* wsim = (const float*)d_in[2];
    const float* wp = (const float*)d_in[3];
    const float* bp = (const float*)d_in[4];
    float* out = (float*)d_out;
    float* ws = (float*)d_ws;

    unsigned short* ET_bf   = (unsigned short*)ws;                 // 4,194,304 bf16
    unsigned short* s1_bf   = (unsigned short*)(ws + 2097152);     // 4,194,304 bf16
    unsigned short* xc_bf   = (unsigned short*)(ws + 4194304);     // 6,553,600 bf16
    unsigned short* xcT_bf  = (unsigned short*)(ws + 7471104);     // 6,815,744 bf16
    unsigned short* yq_bf   = (unsigned short*)(ws + 10878976);    //   409,600 bf16
    unsigned short* xqaT_bf = (unsigned short*)(ws + 11083776);    //   917,504 bf16 [b][448][128]
    unsigned short* wpP_bf  = (unsigned short*)(ws + 11542528);    //   114,688 bf16 [4][128][224]
    float* s_q   = ws + 11599872;   //     2,048 f
    float* cpM   = ws + 11601920;   //    65,536 f
    float* cpS   = ws + 11667456;   //    65,536 f
    float* aP    = ws + 11732992;   // 1,703,936 f
    // total: 13,436,928 floats = 53.7 MB

    k_prep_all<<<2800, 256, 0, stream>>>(xq, wsim, wp, xc, yq_bf, s_q, wpP_bf, xqaT_bf, xc_bf, xcT_bf);
    k_scores_mfma<<<dim3(32, 16), 256, 0, stream>>>(xc_bf, yq_bf, s_q, ET_bf, s1_bf, cpM, cpS);
    k_a_part<<<dim3(13, 4, 16), 256, 0, stream>>>(ET_bf, xcT_bf, cpM, cpS, aP);
    k_acomb2<<<1600, 256, 0, stream>>>(aP, xqaT_bf);
    k_tail<<<dim3(32, 16), 512, 0, stream>>>(s1_bf, xqaT_bf, xc_bf, wpP_bf, bp, out);
}

// Round 11
// 94.513 us; speedup vs baseline: 1.0460x; 1.0460x over previous
//
#include <hip/hip_runtime.h>
#include <hip/hip_bf16.h>

#define Bn 16
#define Cn 2048
#define Qn 128
#define En 200
#define Fn 800
#define On 128
#define EP 208  // padded e-rows for xcT

typedef float f32x4 __attribute__((ext_vector_type(4)));
typedef __bf16 bf16x8 __attribute__((ext_vector_type(8)));

__device__ __forceinline__ unsigned short f2bf(float f) {
    union { float f; unsigned u; } v; v.f = f;
    unsigned r = v.u + 0x7FFF + ((v.u >> 16) & 1);
    return (unsigned short)(r >> 16);
}
__device__ __forceinline__ float bf2f(unsigned short h) {
    union { unsigned u; float f; } v; v.u = (unsigned)h << 16;
    return v.f;
}
__device__ __forceinline__ bf16x8 mul8(bf16x8 a, bf16x8 b) {
    bf16x8 o;
#pragma unroll
    for (int k = 0; k < 8; ++k) o[k] = (__bf16)((float)a[k] * (float)b[k]);
    return o;
}
__device__ __forceinline__ bf16x8 scale8(bf16x8 a, float s) {
    bf16x8 o;
#pragma unroll
    for (int k = 0; k < 8; ++k) o[k] = (__bf16)((float)a[k] * s);
    return o;
}

// ---- k_prep_all: {yq+s_q | wp->bf16 | xq^T | xc->bf16+xc^T} ---------------
__global__ __launch_bounds__(256) void k_prep_all(const float* __restrict__ xq,
                                                  const float* __restrict__ wsim,
                                                  const float* __restrict__ wp,
                                                  const float* __restrict__ xc,
                                                  unsigned short* __restrict__ yqb,
                                                  float* __restrict__ s_q,
                                                  unsigned short* __restrict__ wpb,
                                                  unsigned short* __restrict__ xqaT,
                                                  unsigned short* __restrict__ xcb,
                                                  unsigned short* __restrict__ xcT) {
    int bx = blockIdx.x;
    if (bx < 512) {
        int wid = (bx * 256 + threadIdx.x) >> 6;
        int lane = threadIdx.x & 63;
        const float* xrow = xq + (size_t)wid * En;
        float s = 0.f;
        for (int e = lane; e < En; e += 64) {
            float x = xrow[e];
            yqb[(size_t)wid * En + e] = f2bf(x * wsim[400 + e] + wsim[e]);
            s += x * wsim[200 + e];
        }
        for (int i = 32; i; i >>= 1) s += __shfl_xor(s, i, 64);
        if (lane == 0) s_q[wid] = s;
    } else if (bx < 612) {
        int gid = (bx - 512) * 256 + threadIdx.x;
        int base = gid * 4;
        if (base < On * Fn) {
            float4 v = *(const float4*)(wp + base);
            ushort4 o;
            o.x = f2bf(v.x); o.y = f2bf(v.y); o.z = f2bf(v.z); o.w = f2bf(v.w);
            *(ushort4*)(wpb + base) = o;
        }
    } else if (bx < 740) {
        int lb = bx - 612;                 // 128 blocks: (4 et, 2 qt, 16 b)
        int et = lb & 3, qt = (lb >> 2) & 1, b = lb >> 3;
        int e0 = et * 64, q0 = qt * 64;
        int tid = threadIdx.x;
        __shared__ float t[64][65];
        for (int i = tid; i < 64 * 64; i += 256) {
            int qi = i >> 6, ei = i & 63;
            int e = e0 + ei;
            t[qi][ei] = (e < En) ? xq[((size_t)(b * Qn + q0 + qi)) * En + e] : 0.f;
        }
        __syncthreads();
        for (int i = tid; i < 64 * 64; i += 256) {
            int ei = i >> 6, qi = i & 63;
            int e = e0 + ei;
            if (e < En)
                xqaT[((size_t)(b * 400 + e)) * Qn + q0 + qi] = f2bf(t[qi][ei]);
        }
    } else {
        int lb = bx - 740;                 // 2048 blocks: (32 ct, 4 et, 16 b)
        int ct = lb & 31, et = (lb >> 5) & 3, b = lb >> 7;
        int c0 = ct * 64, e0 = et * 64;
        int tid = threadIdx.x;
        __shared__ float t[64][65];
        for (int i = tid; i < 64 * 64; i += 256) {
            int ci = i >> 6, ei = i & 63;
            int e = e0 + ei;
            t[ci][ei] = (e < En) ? xc[((size_t)(b * Cn + c0 + ci)) * En + e] : 0.f;
        }
        __syncthreads();
        for (int i = tid; i < 64 * 16; i += 256) {
            int ci = i >> 4, g4 = (i & 15) * 4;
            int e = e0 + g4;
            if (e + 3 < En) {
                ushort4 o;
                o.x = f2bf(t[ci][g4]); o.y = f2bf(t[ci][g4 + 1]);
                o.z = f2bf(t[ci][g4 + 2]); o.w = f2bf(t[ci][g4 + 3]);
                *(ushort4*)(xcb + ((size_t)(b * Cn + c0 + ci)) * En + e) = o;
            }
        }
        for (int i = tid; i < 64 * 64; i += 256) {
            int ei = i >> 6, ci = i & 63;
            int e = e0 + ei;
            if (e < EP)
                xcT[((size_t)(b * EP + e)) * Cn + c0 + ci] = f2bf(t[ci][ei]);
        }
    }
}

// ---- k_scores_mfma: scores GEMM + fused row softmax (s1) + block-local ----
__global__ __launch_bounds__(256) void k_scores_mfma(const unsigned short* __restrict__ xcb,
                                                     const unsigned short* __restrict__ yqb,
                                                     const float* __restrict__ s_q,
                                                     unsigned short* __restrict__ ET,
                                                     unsigned short* __restrict__ s1,
                                                     float* __restrict__ cpM,
                                                     float* __restrict__ cpS) {
    int b = blockIdx.y, blk = blockIdx.x, c0 = blk * 64;
    int w = threadIdx.x >> 6, lane = threadIdx.x & 63;
    int lrow = lane & 15, kg = lane >> 4;
    __shared__ float colm4[4][128];
    __shared__ float cols4[4][128];
    const unsigned short* Ab = xcb + ((size_t)(b * Cn + c0 + w * 16 + lrow)) * En + kg * 8;
    const unsigned short* Bb = yqb + ((size_t)(b * Qn + lrow)) * En + kg * 8;
    f32x4 acc[8] = {};
#pragma unroll
    for (int kc = 0; kc < 7; ++kc) {
        bool valid = (kc < 6) || (kg == 0);
        bf16x8 af = bf16x8{0,0,0,0,0,0,0,0};
        if (valid) af = *(const bf16x8*)(Ab + kc * 32);
        bf16x8 bfr[8];
#pragma unroll
        for (int j = 0; j < 8; ++j) {
            bfr[j] = bf16x8{0,0,0,0,0,0,0,0};
            if (valid) bfr[j] = *(const bf16x8*)(Bb + (size_t)j * 16 * En + kc * 32);
        }
#pragma unroll
        for (int j = 0; j < 8; ++j)
            acc[j] = __builtin_amdgcn_mfma_f32_16x16x32_bf16(af, bfr[j], acc[j], 0, 0, 0);
    }
#pragma unroll
    for (int j = 0; j < 8; ++j) {
        float sq = s_q[b * Qn + j * 16 + lrow];
#pragma unroll
        for (int r = 0; r < 4; ++r) acc[j][r] += sq;
    }
    float lm[8], ls[8];
#pragma unroll
    for (int j = 0; j < 8; ++j) {
        float m = fmaxf(fmaxf(acc[j][0], acc[j][1]), fmaxf(acc[j][2], acc[j][3]));
        m = fmaxf(m, __shfl_xor(m, 16, 64));
        m = fmaxf(m, __shfl_xor(m, 32, 64));
        lm[j] = m;
        float s = __expf(acc[j][0] - m) + __expf(acc[j][1] - m)
                + __expf(acc[j][2] - m) + __expf(acc[j][3] - m);
        s += __shfl_xor(s, 16, 64);
        s += __shfl_xor(s, 32, 64);
        ls[j] = s;
    }
    if (kg == 0) {
#pragma unroll
        for (int j = 0; j < 8; ++j) {
            colm4[w][j * 16 + lrow] = lm[j];
            cols4[w][j * 16 + lrow] = ls[j];
        }
    }
    __syncthreads();
    float mb[8];
#pragma unroll
    for (int j = 0; j < 8; ++j) {
        int q = j * 16 + lrow;
        float m = fmaxf(fmaxf(colm4[0][q], colm4[1][q]), fmaxf(colm4[2][q], colm4[3][q]));
        mb[j] = m;
        if (w == 0 && kg == 0) {
            float sb = cols4[0][q] * __expf(colm4[0][q] - m)
                     + cols4[1][q] * __expf(colm4[1][q] - m)
                     + cols4[2][q] * __expf(colm4[2][q] - m)
                     + cols4[3][q] * __expf(colm4[3][q] - m);
            cpM[(b * 32 + blk) * 128 + q] = m;
            cpS[(b * 32 + blk) * 128 + q] = sb;
        }
    }
#pragma unroll
    for (int j = 0; j < 8; ++j) {
        int q = j * 16 + lrow;
        ushort4 o;
        o.x = f2bf(__expf(acc[j][0] - mb[j]));
        o.y = f2bf(__expf(acc[j][1] - mb[j]));
        o.z = f2bf(__expf(acc[j][2] - mb[j]));
        o.w = f2bf(__expf(acc[j][3] - mb[j]));
        *(ushort4*)(ET + ((size_t)(b * Qn + q)) * Cn + c0 + w * 16 + kg * 4) = o;
    }
    size_t rowbase = (size_t)(b * Cn + c0 + w * 16 + kg * 4);
#pragma unroll
    for (int r = 0; r < 4; ++r) {
        float m = acc[0][r];
#pragma unroll
        for (int j = 1; j < 8; ++j) m = fmaxf(m, acc[j][r]);
        for (int d = 1; d < 16; d <<= 1) m = fmaxf(m, __shfl_xor(m, d, 64));
        float ssum = 0.f;
        float e[8];
#pragma unroll
        for (int j = 0; j < 8; ++j) {
            e[j] = __expf(acc[j][r] - m);
            ssum += e[j];
        }
        for (int d = 1; d < 16; d <<= 1) ssum += __shfl_xor(ssum, d, 64);
        float si = 1.f / ssum;
#pragma unroll
        for (int j = 0; j < 8; ++j)
            s1[(rowbase + r) * Qn + j * 16 + lrow] = f2bf(e[j] * si);
    }
}

// ---- k_a_fused: a^T = xcT @ (ET*corr)^T, K split across 4 waves, LDS ------
// reduce, bf16 write straight into xqaT rows [200,400). No global partials.
__global__ __launch_bounds__(256) void k_a_fused(const unsigned short* __restrict__ ET,
                                                 const unsigned short* __restrict__ xcT,
                                                 const float* __restrict__ cpM,
                                                 const float* __restrict__ cpS,
                                                 unsigned short* __restrict__ xqaT) {
    int mt = blockIdx.x, qp = blockIdx.y, b = blockIdx.z;   // 13 x 4 x 16
    int tid = threadIdx.x;
    int w = tid >> 6, lane = tid & 63;
    int lrow = lane & 15, kg = lane >> 4;
    __shared__ float colMs[128], colSis[128];
    __shared__ float red[4][2][16][16];
    if (tid < 128) {
        int q = tid;
        float m = -1e30f;
        for (int k = 0; k < 32; k++) m = fmaxf(m, cpM[(b * 32 + k) * 128 + q]);
        float s = 0.f;
        for (int k = 0; k < 32; k++) s += cpS[(b * 32 + k) * 128 + q] * __expf(cpM[(b * 32 + k) * 128 + q] - m);
        colMs[q] = m;
        colSis[q] = 1.f / s;
    }
    __syncthreads();
    int q0 = qp * 16 + lrow, q1 = q0 + 64;
    float corr0[8], corr1[8];
#pragma unroll
    for (int i = 0; i < 8; ++i) {
        int cb = w * 8 + i;
        corr0[i] = __expf(cpM[(b * 32 + cb) * 128 + q0] - colMs[q0]) * colSis[q0];
        corr1[i] = __expf(cpM[(b * 32 + cb) * 128 + q1] - colMs[q1]) * colSis[q1];
    }
    const unsigned short* Ab = xcT + ((size_t)(b * EP + mt * 16 + lrow)) * Cn + w * 512 + kg * 8;
    const unsigned short* B0 = ET + ((size_t)(b * Qn + q0)) * Cn + w * 512 + kg * 8;
    const unsigned short* B1 = ET + ((size_t)(b * Qn + q1)) * Cn + w * 512 + kg * 8;
    f32x4 acc0 = {}, acc1 = {};
#pragma unroll
    for (int kb = 0; kb < 4; ++kb) {
        bf16x8 af[4], bv0[4], bv1[4];
#pragma unroll
        for (int k4 = 0; k4 < 4; ++k4) {
            af[k4]  = *(const bf16x8*)(Ab + (kb * 4 + k4) * 32);
            bv0[k4] = *(const bf16x8*)(B0 + (kb * 4 + k4) * 32);
            bv1[k4] = *(const bf16x8*)(B1 + (kb * 4 + k4) * 32);
        }
#pragma unroll
        for (int k4 = 0; k4 < 4; ++k4) {
            bf16x8 s0 = scale8(bv0[k4], corr0[kb * 2 + (k4 >> 1)]);
            bf16x8 s1v = scale8(bv1[k4], corr1[kb * 2 + (k4 >> 1)]);
            acc0 = __builtin_amdgcn_mfma_f32_16x16x32_bf16(af[k4], s0, acc0, 0, 0, 0);
            acc1 = __builtin_amdgcn_mfma_f32_16x16x32_bf16(af[k4], s1v, acc1, 0, 0, 0);
        }
    }
#pragma unroll
    for (int r = 0; r < 4; ++r) {
        red[w][0][kg * 4 + r][lrow] = acc0[r];
        red[w][1][kg * 4 + r][lrow] = acc1[r];
    }
    __syncthreads();
    // 512 outputs over 256 threads: (half, row, col)
#pragma unroll
    for (int t = 0; t < 2; ++t) {
        int idx = tid + t * 256;
        int half = idx >> 8, rem = idx & 255;
        int row = rem >> 4, col = rem & 15;
        float s = red[0][half][row][col] + red[1][half][row][col]
                + red[2][half][row][col] + red[3][half][row][col];
        int e = mt * 16 + row;
        int q = qp * 16 + half * 64 + col;
        if (e < En)
            xqaT[((size_t)(b * 400 + 200 + e)) * Qn + q] = f2bf(s);
    }
}

// ---- phase-1 helper: wave owns NJ n-tiles, ALL 4 m-tiles (B reuse = 4) ----
template<int NJ>
__device__ __forceinline__ void cq_phase64(const unsigned short* __restrict__ s1t,
                                           const unsigned short* __restrict__ xqaT_b,
                                           unsigned short* __restrict__ feats,
                                           int J0, int kg, int lrow) {
    f32x4 acc[NJ][4];
#pragma unroll
    for (int j = 0; j < NJ; ++j)
#pragma unroll
        for (int m = 0; m < 4; ++m) acc[j][m] = f32x4{0.f, 0.f, 0.f, 0.f};
#pragma unroll
    for (int kc = 0; kc < 4; ++kc) {
        bf16x8 a[4];
#pragma unroll
        for (int m = 0; m < 4; ++m)
            a[m] = *(const bf16x8*)(s1t + (m * 16 + lrow) * 136 + kg * 8 + kc * 32);
        bf16x8 bv[NJ];
#pragma unroll
        for (int j = 0; j < NJ; ++j)
            bv[j] = *(const bf16x8*)(xqaT_b + ((size_t)((J0 + j) * 16 + lrow)) * Qn + kg * 8 + kc * 32);
#pragma unroll
        for (int j = 0; j < NJ; ++j)
#pragma unroll
            for (int m = 0; m < 4; ++m)
                acc[j][m] = __builtin_amdgcn_mfma_f32_16x16x32_bf16(a[m], bv[j], acc[j][m], 0, 0, 0);
    }
#pragma unroll
    for (int j = 0; j < NJ; ++j) {
        int col = (J0 + j) * 16 + lrow;
        int off = col + (col < 200 ? 200 : 400);
#pragma unroll
        for (int m = 0; m < 4; ++m)
#pragma unroll
            for (int r = 0; r < 4; ++r)
                feats[(m * 16 + kg * 4 + r) * 808 + off] = f2bf(acc[j][m][r]);
    }
}

// ---- k_tail: fused [c2q|q2c] + feats + projection, 64-row tiles -----------
__global__ __launch_bounds__(512, 2) void k_tail(const unsigned short* __restrict__ s1,
                                                 const unsigned short* __restrict__ xqaT,
                                                 const unsigned short* __restrict__ xcb,
                                                 const unsigned short* __restrict__ wpb,
                                                 const float* __restrict__ bp,
                                                 float* __restrict__ out) {
    int b = blockIdx.y, c0 = blockIdx.x * 64;
    int tid = threadIdx.x;
    int w = tid >> 6, lane = tid & 63;
    int lrow = lane & 15, kg = lane >> 4;
    __shared__ unsigned short s1t[64 * 136];
    __shared__ unsigned short feats[64 * 808];

    for (int i = tid; i < 64 * 16; i += 512) {
        int row = i >> 4, c8 = i & 15;
        *(bf16x8*)(s1t + row * 136 + c8 * 8) =
            *(const bf16x8*)(s1 + ((size_t)(b * Cn + c0 + row)) * Qn + c8 * 8);
    }
    for (int i = tid; i < 64 * 25; i += 512) {   // slot0 = xc_bf tile (bf16 direct)
        int row = i / 25, e8 = (i % 25) * 8;
        *(bf16x8*)(feats + row * 808 + e8) =
            *(const bf16x8*)(xcb + ((size_t)(b * Cn + c0 + row)) * En + e8);
    }
    __syncthreads();

    // phase 1: wave w owns n-tiles [3w, 3w+3) (wave 7: [21,25)), all 64 rows
    {
        const unsigned short* xqaT_b = xqaT + (size_t)b * 400 * Qn;
        if (w < 7) cq_phase64<3>(s1t, xqaT_b, feats, w * 3, kg, lrow);
        else       cq_phase64<4>(s1t, xqaT_b, feats, 21, kg, lrow);
    }
    __syncthreads();

    // mid-pass: slot2 = x*c2q, slot3 = x*q2c
    for (int i = tid; i < 64 * 25; i += 512) {
        int row = i / 25, e8 = (i % 25) * 8;
        unsigned short* fr = feats + row * 808;
        bf16x8 x  = *(bf16x8*)(fr + e8);
        bf16x8 c2 = *(bf16x8*)(fr + 200 + e8);
        bf16x8 q2 = *(bf16x8*)(fr + 600 + e8);
        *(bf16x8*)(fr + 400 + e8) = mul8(x, c2);
        *(bf16x8*)(fr + 600 + e8) = mul8(x, q2);
    }
    __syncthreads();

    // phase 2: wave w owns n-tile w (16 cols), all 4 m-tiles. B reuse = 4.
    {
        f32x4 acc[4] = {};
        const unsigned short* Bb = wpb + ((size_t)(w * 16 + lrow)) * Fn + kg * 8;
        const unsigned short* A0 = feats + lrow * 808 + kg * 8;
#pragma unroll
        for (int kc = 0; kc < 25; ++kc) {
            bf16x8 bfr = *(const bf16x8*)(Bb + kc * 32);
#pragma unroll
            for (int m = 0; m < 4; ++m) {
                bf16x8 af = *(const bf16x8*)(A0 + m * 16 * 808 + kc * 32);
                acc[m] = __builtin_amdgcn_mfma_f32_16x16x32_bf16(af, bfr, acc[m], 0, 0, 0);
            }
        }
        int o = w * 16 + lrow;
        float bpv = bp[o];
#pragma unroll
        for (int m = 0; m < 4; ++m)
#pragma unroll
            for (int r = 0; r < 4; ++r)
                out[((size_t)(b * Cn + c0 + m * 16 + kg * 4 + r)) * On + o] = acc[m][r] + bpv;
    }
}

extern "C" void kernel_launch(void* const* d_in, const int* in_sizes, int n_in,
                              void* d_out, int out_size, void* d_ws, size_t ws_size,
                              hipStream_t stream) {
    const float* xc = (const float*)d_in[0];
    const float* xq = (const float*)d_in[1];
    const float* wsim = (const float*)d_in[2];
    const float* wp = (const float*)d_in[3];
    const float* bp = (const float*)d_in[4];
    float* out = (float*)d_out;
    float* ws = (float*)d_ws;

    unsigned short* ET_bf   = (unsigned short*)ws;                 // 4,194,304 bf16
    unsigned short* s1_bf   = (unsigned short*)(ws + 2097152);     // 4,194,304 bf16
    unsigned short* xc_bf   = (unsigned short*)(ws + 4194304);     // 6,553,600 bf16
    unsigned short* xcT_bf  = (unsigned short*)(ws + 7471104);     // 6,815,744 bf16
    unsigned short* yq_bf   = (unsigned short*)(ws + 10878976);    //   409,600 bf16
    unsigned short* xqaT_bf = (unsigned short*)(ws + 11083776);    //   819,200 bf16 [b][400][128]
    unsigned short* wp_bf   = (unsigned short*)(ws + 11493376);    //   102,400 bf16
    float* s_q   = ws + 11544576;   //     2,048 f
    float* cpM   = ws + 11546624;   //    65,536 f
    float* cpS   = ws + 11612160;   //    65,536 f
    // total: 11,677,696 floats = 46.7 MB

    k_prep_all<<<2788, 256, 0, stream>>>(xq, wsim, wp, xc, yq_bf, s_q, wp_bf, xqaT_bf, xc_bf, xcT_bf);
    k_scores_mfma<<<dim3(32, 16), 256, 0, stream>>>(xc_bf, yq_bf, s_q, ET_bf, s1_bf, cpM, cpS);
    k_a_fused<<<dim3(13, 4, 16), 256, 0, stream>>>(ET_bf, xcT_bf, cpM, cpS, xqaT_bf);
    k_tail<<<dim3(32, 16), 512, 0, stream>>>(s1_bf, xqaT_bf, xc_bf, wp_bf, bp, out);
}

// Round 12
// 93.044 us; speedup vs baseline: 1.0626x; 1.0158x over previous
//
#include <hip/hip_runtime.h>
#include <hip/hip_bf16.h>

#define Bn 16
#define Cn 2048
#define Qn 128
#define En 200
#define Fn 800
#define On 128
#define EP 208   // padded e-rows for xcT
#define KP 224   // padded per-slot K for wpP (7 x K32)
#define XR 448   // xqaT rows: [0,224) xq^T (+pad), [224,448) a^T (+pad)
#define BUFP 456 // k_tail buf pitch (912B = 57x16B, odd -> conflict-floor reads)

typedef float f32x4 __attribute__((ext_vector_type(4)));
typedef __bf16 bf16x8 __attribute__((ext_vector_type(8)));

__device__ __forceinline__ unsigned short f2bf(float f) {
    union { float f; unsigned u; } v; v.f = f;
    unsigned r = v.u + 0x7FFF + ((v.u >> 16) & 1);
    return (unsigned short)(r >> 16);
}
__device__ __forceinline__ float bf2f(unsigned short h) {
    union { unsigned u; float f; } v; v.u = (unsigned)h << 16;
    return v.f;
}
__device__ __forceinline__ bf16x8 mul8(bf16x8 a, bf16x8 b) {
    bf16x8 o;
#pragma unroll
    for (int k = 0; k < 8; ++k) o[k] = (__bf16)((float)a[k] * (float)b[k]);
    return o;
}
__device__ __forceinline__ bf16x8 scale8(bf16x8 a, float s) {
    bf16x8 o;
#pragma unroll
    for (int k = 0; k < 8; ++k) o[k] = (__bf16)((float)a[k] * s);
    return o;
}

// ---- k_prep_all: {yq+s_q | wpP | xq^T+pads | xc->bf16+xc^T} ---------------
__global__ __launch_bounds__(256) void k_prep_all(const float* __restrict__ xq,
                                                  const float* __restrict__ wsim,
                                                  const float* __restrict__ wp,
                                                  const float* __restrict__ xc,
                                                  unsigned short* __restrict__ yqb,
                                                  float* __restrict__ s_q,
                                                  unsigned short* __restrict__ wpP,
                                                  unsigned short* __restrict__ xqaT,
                                                  unsigned short* __restrict__ xcb,
                                                  unsigned short* __restrict__ xcT) {
    int bx = blockIdx.x;
    if (bx < 512) {
        int wid = (bx * 256 + threadIdx.x) >> 6;
        int lane = threadIdx.x & 63;
        const float* xrow = xq + (size_t)wid * En;
        float s = 0.f;
        for (int e = lane; e < En; e += 64) {
            float x = xrow[e];
            yqb[(size_t)wid * En + e] = f2bf(x * wsim[400 + e] + wsim[e]);
            s += x * wsim[200 + e];
        }
        for (int i = 32; i; i >>= 1) s += __shfl_xor(s, i, 64);
        if (lane == 0) s_q[wid] = s;
    } else if (bx < 624) {
        // wpP[s][o][k] = wp[o][s*200+k] (k<200) else 0 ; 112 blocks
        int gid = (bx - 512) * 256 + threadIdx.x;
        int flat = gid * 4;                       // < 4*128*224 = 114688
        int s = flat / (On * KP);
        int rem = flat % (On * KP);
        int o = rem / KP, k = rem % KP;
        ushort4 ov = {0, 0, 0, 0};
        if (k < 200) {
            float4 v = *(const float4*)(wp + (size_t)o * Fn + s * 200 + k);
            ov.x = f2bf(v.x); ov.y = f2bf(v.y); ov.z = f2bf(v.z); ov.w = f2bf(v.w);
        }
        *(ushort4*)(wpP + flat) = ov;
    } else if (bx < 752) {
        // xqaT rows [0,200) = xq^T ; zero pads [200,224) & [424,448)
        int lb = bx - 624;                 // 128 blocks: (4 et, 2 qt, 16 b)
        int et = lb & 3, qt = (lb >> 2) & 1, b = lb >> 3;
        int e0 = et * 64, q0 = qt * 64;
        int tid = threadIdx.x;
        __shared__ float t[64][65];
        for (int i = tid; i < 64 * 64; i += 256) {
            int qi = i >> 6, ei = i & 63;
            int e = e0 + ei;
            t[qi][ei] = (e < En) ? xq[((size_t)(b * Qn + q0 + qi)) * En + e] : 0.f;
        }
        __syncthreads();
        for (int i = tid; i < 64 * 64; i += 256) {
            int ei = i >> 6, qi = i & 63;
            int e = e0 + ei;
            if (e < En)
                xqaT[((size_t)(b * XR + e)) * Qn + q0 + qi] = f2bf(t[qi][ei]);
        }
        if (et == 3) {
            for (int i = tid; i < 24 * 64; i += 256) {
                int e = 200 + (i >> 6), q = q0 + (i & 63);
                xqaT[((size_t)(b * XR + e)) * Qn + q] = 0;
            }
            for (int i = tid; i < 24 * 64; i += 256) {
                int e = 424 + (i >> 6), q = q0 + (i & 63);
                xqaT[((size_t)(b * XR + e)) * Qn + q] = 0;
            }
        }
    } else {
        int lb = bx - 752;                 // 2048 blocks: (32 ct, 4 et, 16 b)
        int ct = lb & 31, et = (lb >> 5) & 3, b = lb >> 7;
        int c0 = ct * 64, e0 = et * 64;
        int tid = threadIdx.x;
        __shared__ float t[64][65];
        for (int i = tid; i < 64 * 64; i += 256) {
            int ci = i >> 6, ei = i & 63;
            int e = e0 + ei;
            t[ci][ei] = (e < En) ? xc[((size_t)(b * Cn + c0 + ci)) * En + e] : 0.f;
        }
        __syncthreads();
        for (int i = tid; i < 64 * 16; i += 256) {
            int ci = i >> 4, g4 = (i & 15) * 4;
            int e = e0 + g4;
            if (e + 3 < En) {
                ushort4 o;
                o.x = f2bf(t[ci][g4]); o.y = f2bf(t[ci][g4 + 1]);
                o.z = f2bf(t[ci][g4 + 2]); o.w = f2bf(t[ci][g4 + 3]);
                *(ushort4*)(xcb + ((size_t)(b * Cn + c0 + ci)) * En + e) = o;
            }
        }
        for (int i = tid; i < 64 * 64; i += 256) {
            int ei = i >> 6, ci = i & 63;
            int e = e0 + ei;
            if (e < EP)
                xcT[((size_t)(b * EP + e)) * Cn + c0 + ci] = f2bf(t[ci][ei]);
        }
    }
}

// ---- k_scores_mfma: scores GEMM + fused row softmax (s1) + block-local ----
__global__ __launch_bounds__(256) void k_scores_mfma(const unsigned short* __restrict__ xcb,
                                                     const unsigned short* __restrict__ yqb,
                                                     const float* __restrict__ s_q,
                                                     unsigned short* __restrict__ ET,
                                                     unsigned short* __restrict__ s1,
                                                     float* __restrict__ cpM,
                                                     float* __restrict__ cpS) {
    int b = blockIdx.y, blk = blockIdx.x, c0 = blk * 64;
    int w = threadIdx.x >> 6, lane = threadIdx.x & 63;
    int lrow = lane & 15, kg = lane >> 4;
    __shared__ float colm4[4][128];
    __shared__ float cols4[4][128];
    const unsigned short* Ab = xcb + ((size_t)(b * Cn + c0 + w * 16 + lrow)) * En + kg * 8;
    const unsigned short* Bb = yqb + ((size_t)(b * Qn + lrow)) * En + kg * 8;
    f32x4 acc[8] = {};
#pragma unroll
    for (int kc = 0; kc < 7; ++kc) {
        bool valid = (kc < 6) || (kg == 0);
        bf16x8 af = bf16x8{0,0,0,0,0,0,0,0};
        if (valid) af = *(const bf16x8*)(Ab + kc * 32);
        bf16x8 bfr[8];
#pragma unroll
        for (int j = 0; j < 8; ++j) {
            bfr[j] = bf16x8{0,0,0,0,0,0,0,0};
            if (valid) bfr[j] = *(const bf16x8*)(Bb + (size_t)j * 16 * En + kc * 32);
        }
#pragma unroll
        for (int j = 0; j < 8; ++j)
            acc[j] = __builtin_amdgcn_mfma_f32_16x16x32_bf16(af, bfr[j], acc[j], 0, 0, 0);
    }
#pragma unroll
    for (int j = 0; j < 8; ++j) {
        float sq = s_q[b * Qn + j * 16 + lrow];
#pragma unroll
        for (int r = 0; r < 4; ++r) acc[j][r] += sq;
    }
    float lm[8], ls[8];
#pragma unroll
    for (int j = 0; j < 8; ++j) {
        float m = fmaxf(fmaxf(acc[j][0], acc[j][1]), fmaxf(acc[j][2], acc[j][3]));
        m = fmaxf(m, __shfl_xor(m, 16, 64));
        m = fmaxf(m, __shfl_xor(m, 32, 64));
        lm[j] = m;
        float s = __expf(acc[j][0] - m) + __expf(acc[j][1] - m)
                + __expf(acc[j][2] - m) + __expf(acc[j][3] - m);
        s += __shfl_xor(s, 16, 64);
        s += __shfl_xor(s, 32, 64);
        ls[j] = s;
    }
    if (kg == 0) {
#pragma unroll
        for (int j = 0; j < 8; ++j) {
            colm4[w][j * 16 + lrow] = lm[j];
            cols4[w][j * 16 + lrow] = ls[j];
        }
    }
    __syncthreads();
    float mb[8];
#pragma unroll
    for (int j = 0; j < 8; ++j) {
        int q = j * 16 + lrow;
        float m = fmaxf(fmaxf(colm4[0][q], colm4[1][q]), fmaxf(colm4[2][q], colm4[3][q]));
        mb[j] = m;
        if (w == 0 && kg == 0) {
            float sb = cols4[0][q] * __expf(colm4[0][q] - m)
                     + cols4[1][q] * __expf(colm4[1][q] - m)
                     + cols4[2][q] * __expf(colm4[2][q] - m)
                     + cols4[3][q] * __expf(colm4[3][q] - m);
            cpM[(b * 32 + blk) * 128 + q] = m;
            cpS[(b * 32 + blk) * 128 + q] = sb;
        }
    }
#pragma unroll
    for (int j = 0; j < 8; ++j) {
        int q = j * 16 + lrow;
        ushort4 o;
        o.x = f2bf(__expf(acc[j][0] - mb[j]));
        o.y = f2bf(__expf(acc[j][1] - mb[j]));
        o.z = f2bf(__expf(acc[j][2] - mb[j]));
        o.w = f2bf(__expf(acc[j][3] - mb[j]));
        *(ushort4*)(ET + ((size_t)(b * Qn + q)) * Cn + c0 + w * 16 + kg * 4) = o;
    }
    size_t rowbase = (size_t)(b * Cn + c0 + w * 16 + kg * 4);
#pragma unroll
    for (int r = 0; r < 4; ++r) {
        float m = acc[0][r];
#pragma unroll
        for (int j = 1; j < 8; ++j) m = fmaxf(m, acc[j][r]);
        for (int d = 1; d < 16; d <<= 1) m = fmaxf(m, __shfl_xor(m, d, 64));
        float ssum = 0.f;
        float e[8];
#pragma unroll
        for (int j = 0; j < 8; ++j) {
            e[j] = __expf(acc[j][r] - m);
            ssum += e[j];
        }
        for (int d = 1; d < 16; d <<= 1) ssum += __shfl_xor(ssum, d, 64);
        float si = 1.f / ssum;
#pragma unroll
        for (int j = 0; j < 8; ++j)
            s1[(rowbase + r) * Qn + j * 16 + lrow] = f2bf(e[j] * si);
    }
}

// ---- k_a_fused: a^T = xcT @ (ET*corr)^T, K split across 4 waves, LDS ------
__global__ __launch_bounds__(256) void k_a_fused(const unsigned short* __restrict__ ET,
                                                 const unsigned short* __restrict__ xcT,
                                                 const float* __restrict__ cpM,
                                                 const float* __restrict__ cpS,
                                                 unsigned short* __restrict__ xqaT) {
    int mt = blockIdx.x, qp = blockIdx.y, b = blockIdx.z;   // 13 x 4 x 16
    int tid = threadIdx.x;
    int w = tid >> 6, lane = tid & 63;
    int lrow = lane & 15, kg = lane >> 4;
    __shared__ float colMs[128], colSis[128];
    __shared__ float red[4][2][16][16];
    if (tid < 128) {
        int q = tid;
        float m = -1e30f;
        for (int k = 0; k < 32; k++) m = fmaxf(m, cpM[(b * 32 + k) * 128 + q]);
        float s = 0.f;
        for (int k = 0; k < 32; k++) s += cpS[(b * 32 + k) * 128 + q] * __expf(cpM[(b * 32 + k) * 128 + q] - m);
        colMs[q] = m;
        colSis[q] = 1.f / s;
    }
    __syncthreads();
    int q0 = qp * 16 + lrow, q1 = q0 + 64;
    float corr0[8], corr1[8];
#pragma unroll
    for (int i = 0; i < 8; ++i) {
        int cb = w * 8 + i;
        corr0[i] = __expf(cpM[(b * 32 + cb) * 128 + q0] - colMs[q0]) * colSis[q0];
        corr1[i] = __expf(cpM[(b * 32 + cb) * 128 + q1] - colMs[q1]) * colSis[q1];
    }
    const unsigned short* Ab = xcT + ((size_t)(b * EP + mt * 16 + lrow)) * Cn + w * 512 + kg * 8;
    const unsigned short* B0 = ET + ((size_t)(b * Qn + q0)) * Cn + w * 512 + kg * 8;
    const unsigned short* B1 = ET + ((size_t)(b * Qn + q1)) * Cn + w * 512 + kg * 8;
    f32x4 acc0 = {}, acc1 = {};
#pragma unroll
    for (int kb = 0; kb < 4; ++kb) {
        bf16x8 af[4], bv0[4], bv1[4];
#pragma unroll
        for (int k4 = 0; k4 < 4; ++k4) {
            af[k4]  = *(const bf16x8*)(Ab + (kb * 4 + k4) * 32);
            bv0[k4] = *(const bf16x8*)(B0 + (kb * 4 + k4) * 32);
            bv1[k4] = *(const bf16x8*)(B1 + (kb * 4 + k4) * 32);
        }
#pragma unroll
        for (int k4 = 0; k4 < 4; ++k4) {
            bf16x8 s0 = scale8(bv0[k4], corr0[kb * 2 + (k4 >> 1)]);
            bf16x8 s1v = scale8(bv1[k4], corr1[kb * 2 + (k4 >> 1)]);
            acc0 = __builtin_amdgcn_mfma_f32_16x16x32_bf16(af[k4], s0, acc0, 0, 0, 0);
            acc1 = __builtin_amdgcn_mfma_f32_16x16x32_bf16(af[k4], s1v, acc1, 0, 0, 0);
        }
    }
#pragma unroll
    for (int r = 0; r < 4; ++r) {
        red[w][0][kg * 4 + r][lrow] = acc0[r];
        red[w][1][kg * 4 + r][lrow] = acc1[r];
    }
    __syncthreads();
#pragma unroll
    for (int t = 0; t < 2; ++t) {
        int idx = tid + t * 256;
        int half = idx >> 8, rem = idx & 255;
        int row = rem >> 4, col = rem & 15;
        float s = red[0][half][row][col] + red[1][half][row][col]
                + red[2][half][row][col] + red[3][half][row][col];
        int e = mt * 16 + row;
        int q = qp * 16 + half * 64 + col;
        if (e < En)
            xqaT[((size_t)(b * XR + 224 + e)) * Qn + q] = f2bf(s);
    }
}

// ---- cq helpers: NJ n-tiles x 4 m-tiles of s1t @ xrows --------------------
template<int NJ>
__device__ __forceinline__ void cq2_regs(const unsigned short* __restrict__ s1t,
                                         const unsigned short* __restrict__ xrows,
                                         f32x4 (&acc)[NJ][4], int J0, int kg, int lrow) {
#pragma unroll
    for (int j = 0; j < NJ; ++j)
#pragma unroll
        for (int m = 0; m < 4; ++m) acc[j][m] = f32x4{0.f, 0.f, 0.f, 0.f};
#pragma unroll
    for (int kc = 0; kc < 4; ++kc) {
        bf16x8 a[4];
#pragma unroll
        for (int m = 0; m < 4; ++m)
            a[m] = *(const bf16x8*)(s1t + (m * 16 + lrow) * 136 + kg * 8 + kc * 32);
        bf16x8 bv[NJ];
#pragma unroll
        for (int j = 0; j < NJ; ++j)
            bv[j] = *(const bf16x8*)(xrows + ((size_t)((J0 + j) * 16 + lrow)) * Qn + kg * 8 + kc * 32);
#pragma unroll
        for (int j = 0; j < NJ; ++j)
#pragma unroll
            for (int m = 0; m < 4; ++m)
                acc[j][m] = __builtin_amdgcn_mfma_f32_16x16x32_bf16(a[m], bv[j], acc[j][m], 0, 0, 0);
    }
}

template<int NJ>
__device__ __forceinline__ void cq2_store(const unsigned short* __restrict__ s1t,
                                          const unsigned short* __restrict__ xrows,
                                          unsigned short* __restrict__ dst,  // buf + 224
                                          int J0, int kg, int lrow) {
    f32x4 acc[NJ][4];
    cq2_regs<NJ>(s1t, xrows, acc, J0, kg, lrow);
#pragma unroll
    for (int j = 0; j < NJ; ++j) {
        int col = (J0 + j) * 16 + lrow;
#pragma unroll
        for (int m = 0; m < 4; ++m)
#pragma unroll
            for (int r = 0; r < 4; ++r)
                dst[(m * 16 + kg * 4 + r) * BUFP + col] = f2bf(acc[j][m][r]);
    }
}

template<int NJ>
__device__ __forceinline__ void mul_scatter(unsigned short* __restrict__ buf,  // S_A base
                                            f32x4 (&acc)[NJ][4], int J0, int kg, int lrow) {
#pragma unroll
    for (int j = 0; j < NJ; ++j) {
        int col = (J0 + j) * 16 + lrow;
#pragma unroll
        for (int m = 0; m < 4; ++m)
#pragma unroll
            for (int r = 0; r < 4; ++r) {
                int idx = (m * 16 + kg * 4 + r) * BUFP + col;
                buf[idx] = f2bf(bf2f(buf[idx]) * acc[j][m][r]);
            }
    }
}

// proj segment: acc += A(buf seg, K=224) @ B(wpP slot, K=224)
__device__ __forceinline__ void proj_seg(f32x4 (&acc)[4],
                                         const unsigned short* __restrict__ Aseg,  // buf + seg*224 (+row offsets inside)
                                         const unsigned short* __restrict__ Bslot, // wpP + slot*On*KP + o*KP
                                         int kg, int lrow) {
    bf16x8 bv[7];
#pragma unroll
    for (int kc = 0; kc < 7; ++kc)
        bv[kc] = *(const bf16x8*)(Bslot + kg * 8 + kc * 32);
#pragma unroll
    for (int kc = 0; kc < 7; ++kc) {
#pragma unroll
        for (int m = 0; m < 4; ++m) {
            bf16x8 af = *(const bf16x8*)(Aseg + (m * 16 + lrow) * BUFP + kg * 8 + kc * 32);
            acc[m] = __builtin_amdgcn_mfma_f32_16x16x32_bf16(af, bv[kc], acc[m], 0, 0, 0);
        }
    }
}

// ---- k_tail: split-K slot fusion, 64-row tiles, 75.8 KB LDS -> 2 blk/CU ---
// half1 = [x | c2q] @ wp[slot0|slot1]; half2 = [x*q2c | x*c2q] @ wp[slot3|slot2]
__global__ __launch_bounds__(512, 4) void k_tail(const unsigned short* __restrict__ s1,
                                                 const unsigned short* __restrict__ xqaT,
                                                 const unsigned short* __restrict__ xcb,
                                                 const unsigned short* __restrict__ wpP,
                                                 const float* __restrict__ bp,
                                                 float* __restrict__ out) {
    int b = blockIdx.y, c0 = blockIdx.x * 64;
    int tid = threadIdx.x;
    int w = tid >> 6, lane = tid & 63;
    int lrow = lane & 15, kg = lane >> 4;
    __shared__ unsigned short s1t[64 * 136];   // 17.4 KB
    __shared__ unsigned short buf[64 * BUFP];  // 58.4 KB: S_A cols[0,224), S_B cols[224,448)

    for (int i = tid; i < 64 * 16; i += 512) {
        int row = i >> 4, c8 = i & 15;
        *(bf16x8*)(s1t + row * 136 + c8 * 8) =
            *(const bf16x8*)(s1 + ((size_t)(b * Cn + c0 + row)) * Qn + c8 * 8);
    }
    for (int i = tid; i < 64 * 28; i += 512) {   // S_A = x (chunks 25..27 zero)
        int row = i / 28, c8 = i % 28;
        bf16x8 v = bf16x8{0,0,0,0,0,0,0,0};
        if (c8 < 25) v = *(const bf16x8*)(xcb + ((size_t)(b * Cn + c0 + row)) * En + c8 * 8);
        *(bf16x8*)(buf + row * BUFP + c8 * 8) = v;
    }
    __syncthreads();

    const unsigned short* xq_b = xqaT + (size_t)b * XR * Qn;

    // ph1a: c2q -> S_B (14 n-tiles over 8 waves)
    if (w < 6)       cq2_store<2>(s1t, xq_b, buf + 224, 2 * w, kg, lrow);
    else if (w == 6) cq2_store<1>(s1t, xq_b, buf + 224, 12, kg, lrow);
    else             cq2_store<1>(s1t, xq_b, buf + 224, 13, kg, lrow);
    __syncthreads();

    // ph2a: acc += x @ slot0 + c2q @ slot1
    f32x4 acc[4] = {};
    {
        const unsigned short* Bo = wpP + ((size_t)(w * 16 + lrow)) * KP;
        proj_seg(acc, buf,       Bo,                        kg, lrow);
        proj_seg(acc, buf + 224, Bo + (size_t)1 * On * KP,  kg, lrow);
    }

    // ph1b: q2c fragments in regs
    f32x4 aq2[2][4];
    if (w < 6)       cq2_regs<2>(s1t, xq_b + (size_t)224 * Qn, aq2, 2 * w, kg, lrow);
    else if (w == 6) { f32x4 t1[1][4]; cq2_regs<1>(s1t, xq_b + (size_t)224 * Qn, t1, 12, kg, lrow);
                       aq2[0][0]=t1[0][0]; aq2[0][1]=t1[0][1]; aq2[0][2]=t1[0][2]; aq2[0][3]=t1[0][3]; }
    else             { f32x4 t1[1][4]; cq2_regs<1>(s1t, xq_b + (size_t)224 * Qn, t1, 13, kg, lrow);
                       aq2[0][0]=t1[0][0]; aq2[0][1]=t1[0][1]; aq2[0][2]=t1[0][2]; aq2[0][3]=t1[0][3]; }
    __syncthreads();

    // mid: S_B = x * c2q (vectorized, amortized across 512 threads)
    for (int i = tid; i < 64 * 28; i += 512) {
        int row = i / 28, c8 = i % 28;
        unsigned short* fr = buf + row * BUFP;
        bf16x8 x  = *(bf16x8*)(fr + c8 * 8);
        bf16x8 c2 = *(bf16x8*)(fr + 224 + c8 * 8);
        *(bf16x8*)(fr + 224 + c8 * 8) = mul8(x, c2);
    }
    __syncthreads();

    // scatter: S_A = x * q2c (self-located: lane reads+writes same slot)
    if (w < 6)       mul_scatter<2>(buf, aq2, 2 * w, kg, lrow);
    else if (w == 6) { f32x4 t1[1][4]; t1[0][0]=aq2[0][0]; t1[0][1]=aq2[0][1]; t1[0][2]=aq2[0][2]; t1[0][3]=aq2[0][3];
                       mul_scatter<1>(buf, t1, 12, kg, lrow); }
    else             { f32x4 t1[1][4]; t1[0][0]=aq2[0][0]; t1[0][1]=aq2[0][1]; t1[0][2]=aq2[0][2]; t1[0][3]=aq2[0][3];
                       mul_scatter<1>(buf, t1, 13, kg, lrow); }
    __syncthreads();

    // ph2b: acc += (x*q2c) @ slot3 + (x*c2q) @ slot2
    {
        const unsigned short* Bo = wpP + ((size_t)(w * 16 + lrow)) * KP;
        proj_seg(acc, buf,       Bo + (size_t)3 * On * KP, kg, lrow);
        proj_seg(acc, buf + 224, Bo + (size_t)2 * On * KP, kg, lrow);
    }

    int o = w * 16 + lrow;
    float bpv = bp[o];
#pragma unroll
    for (int m = 0; m < 4; ++m)
#pragma unroll
        for (int r = 0; r < 4; ++r)
            out[((size_t)(b * Cn + c0 + m * 16 + kg * 4 + r)) * On + o] = acc[m][r] + bpv;
}

extern "C" void kernel_launch(void* const* d_in, const int* in_sizes, int n_in,
                              void* d_out, int out_size, void* d_ws, size_t ws_size,
                              hipStream_t stream) {
    const float* xc = (const float*)d_in[0];
    const float* xq = (const float*)d_in[1];
    const float* wsim = (const float*)d_in[2];
    const float* wp = (const float*)d_in[3];
    const float* bp = (const float*)d_in[4];
    float* out = (float*)d_out;
    float* ws = (float*)d_ws;

    unsigned short* ET_bf   = (unsigned short*)ws;                 // 4,194,304 bf16
    unsigned short* s1_bf   = (unsigned short*)(ws + 2097152);     // 4,194,304 bf16
    unsigned short* xc_bf   = (unsigned short*)(ws + 4194304);     // 6,553,600 bf16
    unsigned short* xcT_bf  = (unsigned short*)(ws + 7471104);     // 6,815,744 bf16
    unsigned short* yq_bf   = (unsigned short*)(ws + 10878976);    //   409,600 bf16
    unsigned short* xqaT_bf = (unsigned short*)(ws + 11083776);    //   917,504 bf16 [b][448][128]
    unsigned short* wpP_bf  = (unsigned short*)(ws + 11542528);    //   114,688 bf16 [4][128][224]
    float* s_q   = ws + 11599872;   //     2,048 f
    float* cpM   = ws + 11601920;   //    65,536 f
    float* cpS   = ws + 11667456;   //    65,536 f
    // total: 11,732,992 floats = 46.9 MB

    k_prep_all<<<2800, 256, 0, stream>>>(xq, wsim, wp, xc, yq_bf, s_q, wpP_bf, xqaT_bf, xc_bf, xcT_bf);
    k_scores_mfma<<<dim3(32, 16), 256, 0, stream>>>(xc_bf, yq_bf, s_q, ET_bf, s1_bf, cpM, cpS);
    k_a_fused<<<dim3(13, 4, 16), 256, 0, stream>>>(ET_bf, xcT_bf, cpM, cpS, xqaT_bf);
    k_tail<<<dim3(32, 16), 512, 0, stream>>>(s1_bf, xqaT_bf, xc_bf, wpP_bf, bp, out);
}

// Round 13
// 91.005 us; speedup vs baseline: 1.0864x; 1.0224x over previous
//
#include <hip/hip_runtime.h>
#include <hip/hip_bf16.h>

#define Bn 16
#define Cn 2048
#define Qn 128
#define En 200
#define Fn 800
#define On 128
#define EP 208   // padded e-rows for xcT
#define KP 224   // padded per-slot K for wpP (7 x K32)
#define XR 448   // xqaT rows: [0,224) xq^T (+pad), [224,448) a^T (+pad)
#define BUFP 456 // k_tail buf pitch (912B = 57x16B, odd -> conflict-floor reads)

typedef float f32x4 __attribute__((ext_vector_type(4)));
typedef __bf16 bf16x8 __attribute__((ext_vector_type(8)));

__device__ __forceinline__ unsigned short f2bf(float f) {
    union { float f; unsigned u; } v; v.f = f;
    unsigned r = v.u + 0x7FFF + ((v.u >> 16) & 1);
    return (unsigned short)(r >> 16);
}
__device__ __forceinline__ float bf2f(unsigned short h) {
    union { unsigned u; float f; } v; v.u = (unsigned)h << 16;
    return v.f;
}
__device__ __forceinline__ bf16x8 mul8(bf16x8 a, bf16x8 b) {
    bf16x8 o;
#pragma unroll
    for (int k = 0; k < 8; ++k) o[k] = (__bf16)((float)a[k] * (float)b[k]);
    return o;
}
__device__ __forceinline__ bf16x8 scale8(bf16x8 a, float s) {
    bf16x8 o;
#pragma unroll
    for (int k = 0; k < 8; ++k) o[k] = (__bf16)((float)a[k] * s);
    return o;
}

// ---- k_prep_all: {yq+s_q | wpP | xq^T+pads | xc->bf16+xc^T} ---------------
__global__ __launch_bounds__(256) void k_prep_all(const float* __restrict__ xq,
                                                  const float* __restrict__ wsim,
                                                  const float* __restrict__ wp,
                                                  const float* __restrict__ xc,
                                                  unsigned short* __restrict__ yqb,
                                                  float* __restrict__ s_q,
                                                  unsigned short* __restrict__ wpP,
                                                  unsigned short* __restrict__ xqaT,
                                                  unsigned short* __restrict__ xcb,
                                                  unsigned short* __restrict__ xcT) {
    int bx = blockIdx.x;
    if (bx < 512) {
        int wid = (bx * 256 + threadIdx.x) >> 6;
        int lane = threadIdx.x & 63;
        const float* xrow = xq + (size_t)wid * En;
        float s = 0.f;
        for (int e = lane; e < En; e += 64) {
            float x = xrow[e];
            yqb[(size_t)wid * En + e] = f2bf(x * wsim[400 + e] + wsim[e]);
            s += x * wsim[200 + e];
        }
        for (int i = 32; i; i >>= 1) s += __shfl_xor(s, i, 64);
        if (lane == 0) s_q[wid] = s;
    } else if (bx < 624) {
        // wpP[s][o][k] = wp[o][s*200+k] (k<200) else 0 ; 112 blocks
        int gid = (bx - 512) * 256 + threadIdx.x;
        int flat = gid * 4;                       // < 4*128*224 = 114688
        int s = flat / (On * KP);
        int rem = flat % (On * KP);
        int o = rem / KP, k = rem % KP;
        ushort4 ov = {0, 0, 0, 0};
        if (k < 200) {
            float4 v = *(const float4*)(wp + (size_t)o * Fn + s * 200 + k);
            ov.x = f2bf(v.x); ov.y = f2bf(v.y); ov.z = f2bf(v.z); ov.w = f2bf(v.w);
        }
        *(ushort4*)(wpP + flat) = ov;
    } else if (bx < 752) {
        // xqaT rows [0,200) = xq^T ; zero pads [200,224) & [424,448)
        int lb = bx - 624;                 // 128 blocks: (4 et, 2 qt, 16 b)
        int et = lb & 3, qt = (lb >> 2) & 1, b = lb >> 3;
        int e0 = et * 64, q0 = qt * 64;
        int tid = threadIdx.x;
        __shared__ float t[64][65];
        for (int i = tid; i < 64 * 64; i += 256) {
            int qi = i >> 6, ei = i & 63;
            int e = e0 + ei;
            t[qi][ei] = (e < En) ? xq[((size_t)(b * Qn + q0 + qi)) * En + e] : 0.f;
        }
        __syncthreads();
        for (int i = tid; i < 64 * 64; i += 256) {
            int ei = i >> 6, qi = i & 63;
            int e = e0 + ei;
            if (e < En)
                xqaT[((size_t)(b * XR + e)) * Qn + q0 + qi] = f2bf(t[qi][ei]);
        }
        if (et == 3) {
            for (int i = tid; i < 24 * 64; i += 256) {
                int e = 200 + (i >> 6), q = q0 + (i & 63);
                xqaT[((size_t)(b * XR + e)) * Qn + q] = 0;
            }
            for (int i = tid; i < 24 * 64; i += 256) {
                int e = 424 + (i >> 6), q = q0 + (i & 63);
                xqaT[((size_t)(b * XR + e)) * Qn + q] = 0;
            }
        }
    } else {
        int lb = bx - 752;                 // 2048 blocks: (32 ct, 4 et, 16 b)
        int ct = lb & 31, et = (lb >> 5) & 3, b = lb >> 7;
        int c0 = ct * 64, e0 = et * 64;
        int tid = threadIdx.x;
        __shared__ float t[64][65];
        for (int i = tid; i < 64 * 64; i += 256) {
            int ci = i >> 6, ei = i & 63;
            int e = e0 + ei;
            t[ci][ei] = (e < En) ? xc[((size_t)(b * Cn + c0 + ci)) * En + e] : 0.f;
        }
        __syncthreads();
        for (int i = tid; i < 64 * 16; i += 256) {
            int ci = i >> 4, g4 = (i & 15) * 4;
            int e = e0 + g4;
            if (e + 3 < En) {
                ushort4 o;
                o.x = f2bf(t[ci][g4]); o.y = f2bf(t[ci][g4 + 1]);
                o.z = f2bf(t[ci][g4 + 2]); o.w = f2bf(t[ci][g4 + 3]);
                *(ushort4*)(xcb + ((size_t)(b * Cn + c0 + ci)) * En + e) = o;
            }
        }
        for (int i = tid; i < 64 * 64; i += 256) {
            int ei = i >> 6, ci = i & 63;
            int e = e0 + ei;
            if (e < EP)
                xcT[((size_t)(b * EP + e)) * Cn + c0 + ci] = f2bf(t[ci][ei]);
        }
    }
}

// ---- k_scores_mfma: scores GEMM + fused row softmax (s1) + block-local ----
// 1D grid (512) with XCD-aware decode: all 32 c-blocks of batch b share an XCD
__global__ __launch_bounds__(256) void k_scores_mfma(const unsigned short* __restrict__ xcb,
                                                     const unsigned short* __restrict__ yqb,
                                                     const float* __restrict__ s_q,
                                                     unsigned short* __restrict__ ET,
                                                     unsigned short* __restrict__ s1,
                                                     float* __restrict__ cpM,
                                                     float* __restrict__ cpS) {
    int bid = blockIdx.x;
    int xcd = bid & 7, idx = bid >> 3;     // idx < 64
    int b = xcd + 8 * (idx >> 5);
    int blk = idx & 31;
    int c0 = blk * 64;
    int w = threadIdx.x >> 6, lane = threadIdx.x & 63;
    int lrow = lane & 15, kg = lane >> 4;
    __shared__ float colm4[4][128];
    __shared__ float cols4[4][128];
    const unsigned short* Ab = xcb + ((size_t)(b * Cn + c0 + w * 16 + lrow)) * En + kg * 8;
    const unsigned short* Bb = yqb + ((size_t)(b * Qn + lrow)) * En + kg * 8;
    f32x4 acc[8] = {};
#pragma unroll
    for (int kc = 0; kc < 7; ++kc) {
        bool valid = (kc < 6) || (kg == 0);
        bf16x8 af = bf16x8{0,0,0,0,0,0,0,0};
        if (valid) af = *(const bf16x8*)(Ab + kc * 32);
        bf16x8 bfr[8];
#pragma unroll
        for (int j = 0; j < 8; ++j) {
            bfr[j] = bf16x8{0,0,0,0,0,0,0,0};
            if (valid) bfr[j] = *(const bf16x8*)(Bb + (size_t)j * 16 * En + kc * 32);
        }
#pragma unroll
        for (int j = 0; j < 8; ++j)
            acc[j] = __builtin_amdgcn_mfma_f32_16x16x32_bf16(af, bfr[j], acc[j], 0, 0, 0);
    }
#pragma unroll
    for (int j = 0; j < 8; ++j) {
        float sq = s_q[b * Qn + j * 16 + lrow];
#pragma unroll
        for (int r = 0; r < 4; ++r) acc[j][r] += sq;
    }
    float lm[8], ls[8];
#pragma unroll
    for (int j = 0; j < 8; ++j) {
        float m = fmaxf(fmaxf(acc[j][0], acc[j][1]), fmaxf(acc[j][2], acc[j][3]));
        m = fmaxf(m, __shfl_xor(m, 16, 64));
        m = fmaxf(m, __shfl_xor(m, 32, 64));
        lm[j] = m;
        float s = __expf(acc[j][0] - m) + __expf(acc[j][1] - m)
                + __expf(acc[j][2] - m) + __expf(acc[j][3] - m);
        s += __shfl_xor(s, 16, 64);
        s += __shfl_xor(s, 32, 64);
        ls[j] = s;
    }
    if (kg == 0) {
#pragma unroll
        for (int j = 0; j < 8; ++j) {
            colm4[w][j * 16 + lrow] = lm[j];
            cols4[w][j * 16 + lrow] = ls[j];
        }
    }
    __syncthreads();
    float mb[8];
#pragma unroll
    for (int j = 0; j < 8; ++j) {
        int q = j * 16 + lrow;
        float m = fmaxf(fmaxf(colm4[0][q], colm4[1][q]), fmaxf(colm4[2][q], colm4[3][q]));
        mb[j] = m;
        if (w == 0 && kg == 0) {
            float sb = cols4[0][q] * __expf(colm4[0][q] - m)
                     + cols4[1][q] * __expf(colm4[1][q] - m)
                     + cols4[2][q] * __expf(colm4[2][q] - m)
                     + cols4[3][q] * __expf(colm4[3][q] - m);
            cpM[(b * 32 + blk) * 128 + q] = m;
            cpS[(b * 32 + blk) * 128 + q] = sb;
        }
    }
#pragma unroll
    for (int j = 0; j < 8; ++j) {
        int q = j * 16 + lrow;
        ushort4 o;
        o.x = f2bf(__expf(acc[j][0] - mb[j]));
        o.y = f2bf(__expf(acc[j][1] - mb[j]));
        o.z = f2bf(__expf(acc[j][2] - mb[j]));
        o.w = f2bf(__expf(acc[j][3] - mb[j]));
        *(ushort4*)(ET + ((size_t)(b * Qn + q)) * Cn + c0 + w * 16 + kg * 4) = o;
    }
    size_t rowbase = (size_t)(b * Cn + c0 + w * 16 + kg * 4);
#pragma unroll
    for (int r = 0; r < 4; ++r) {
        float m = acc[0][r];
#pragma unroll
        for (int j = 1; j < 8; ++j) m = fmaxf(m, acc[j][r]);
        for (int d = 1; d < 16; d <<= 1) m = fmaxf(m, __shfl_xor(m, d, 64));
        float ssum = 0.f;
        float e[8];
#pragma unroll
        for (int j = 0; j < 8; ++j) {
            e[j] = __expf(acc[j][r] - m);
            ssum += e[j];
        }
        for (int d = 1; d < 16; d <<= 1) ssum += __shfl_xor(ssum, d, 64);
        float si = 1.f / ssum;
#pragma unroll
        for (int j = 0; j < 8; ++j)
            s1[(rowbase + r) * Qn + j * 16 + lrow] = f2bf(e[j] * si);
    }
}

// ---- k_a_fused: a^T = xcT @ (ET*corr)^T; XCD-aware: all 52 blocks of a ----
// batch (13 mt x 4 qp) share one XCD -> ET/xcT L2-resident.
__global__ __launch_bounds__(256) void k_a_fused(const unsigned short* __restrict__ ET,
                                                 const unsigned short* __restrict__ xcT,
                                                 const float* __restrict__ cpM,
                                                 const float* __restrict__ cpS,
                                                 unsigned short* __restrict__ xqaT) {
    int bid = blockIdx.x;                 // 832 blocks
    int xcd = bid & 7, idx = bid >> 3;    // idx < 104
    int b = xcd + 8 * (idx / 52);
    int r52 = idx % 52;
    int mt = r52 % 13, qp = r52 / 13;
    int tid = threadIdx.x;
    int w = tid >> 6, lane = tid & 63;
    int lrow = lane & 15, kg = lane >> 4;
    __shared__ float colMs[128], colSis[128];
    __shared__ float red[4][2][16][16];
    if (tid < 128) {
        int q = tid;
        float m = -1e30f;
        for (int k = 0; k < 32; k++) m = fmaxf(m, cpM[(b * 32 + k) * 128 + q]);
        float s = 0.f;
        for (int k = 0; k < 32; k++) s += cpS[(b * 32 + k) * 128 + q] * __expf(cpM[(b * 32 + k) * 128 + q] - m);
        colMs[q] = m;
        colSis[q] = 1.f / s;
    }
    __syncthreads();
    int q0 = qp * 16 + lrow, q1 = q0 + 64;
    float corr0[8], corr1[8];
#pragma unroll
    for (int i = 0; i < 8; ++i) {
        int cb = w * 8 + i;
        corr0[i] = __expf(cpM[(b * 32 + cb) * 128 + q0] - colMs[q0]) * colSis[q0];
        corr1[i] = __expf(cpM[(b * 32 + cb) * 128 + q1] - colMs[q1]) * colSis[q1];
    }
    const unsigned short* Ab = xcT + ((size_t)(b * EP + mt * 16 + lrow)) * Cn + w * 512 + kg * 8;
    const unsigned short* B0 = ET + ((size_t)(b * Qn + q0)) * Cn + w * 512 + kg * 8;
    const unsigned short* B1 = ET + ((size_t)(b * Qn + q1)) * Cn + w * 512 + kg * 8;
    f32x4 acc0 = {}, acc1 = {};
#pragma unroll
    for (int kb = 0; kb < 4; ++kb) {
        bf16x8 af[4], bv0[4], bv1[4];
#pragma unroll
        for (int k4 = 0; k4 < 4; ++k4) {
            af[k4]  = *(const bf16x8*)(Ab + (kb * 4 + k4) * 32);
            bv0[k4] = *(const bf16x8*)(B0 + (kb * 4 + k4) * 32);
            bv1[k4] = *(const bf16x8*)(B1 + (kb * 4 + k4) * 32);
        }
#pragma unroll
        for (int k4 = 0; k4 < 4; ++k4) {
            bf16x8 s0 = scale8(bv0[k4], corr0[kb * 2 + (k4 >> 1)]);
            bf16x8 s1v = scale8(bv1[k4], corr1[kb * 2 + (k4 >> 1)]);
            acc0 = __builtin_amdgcn_mfma_f32_16x16x32_bf16(af[k4], s0, acc0, 0, 0, 0);
            acc1 = __builtin_amdgcn_mfma_f32_16x16x32_bf16(af[k4], s1v, acc1, 0, 0, 0);
        }
    }
#pragma unroll
    for (int r = 0; r < 4; ++r) {
        red[w][0][kg * 4 + r][lrow] = acc0[r];
        red[w][1][kg * 4 + r][lrow] = acc1[r];
    }
    __syncthreads();
#pragma unroll
    for (int t = 0; t < 2; ++t) {
        int idx2 = tid + t * 256;
        int half = idx2 >> 8, rem = idx2 & 255;
        int row = rem >> 4, col = rem & 15;
        float s = red[0][half][row][col] + red[1][half][row][col]
                + red[2][half][row][col] + red[3][half][row][col];
        int e = mt * 16 + row;
        int q = qp * 16 + half * 64 + col;
        if (e < En)
            xqaT[((size_t)(b * XR + 224 + e)) * Qn + q] = f2bf(s);
    }
}

// ---- cq helpers: NJ n-tiles x 4 m-tiles of s1t @ xrows --------------------
template<int NJ>
__device__ __forceinline__ void cq2_regs(const unsigned short* __restrict__ s1t,
                                         const unsigned short* __restrict__ xrows,
                                         f32x4 (&acc)[NJ][4], int J0, int kg, int lrow) {
#pragma unroll
    for (int j = 0; j < NJ; ++j)
#pragma unroll
        for (int m = 0; m < 4; ++m) acc[j][m] = f32x4{0.f, 0.f, 0.f, 0.f};
#pragma unroll
    for (int kc = 0; kc < 4; ++kc) {
        bf16x8 a[4];
#pragma unroll
        for (int m = 0; m < 4; ++m)
            a[m] = *(const bf16x8*)(s1t + (m * 16 + lrow) * 136 + kg * 8 + kc * 32);
        bf16x8 bv[NJ];
#pragma unroll
        for (int j = 0; j < NJ; ++j)
            bv[j] = *(const bf16x8*)(xrows + ((size_t)((J0 + j) * 16 + lrow)) * Qn + kg * 8 + kc * 32);
#pragma unroll
        for (int j = 0; j < NJ; ++j)
#pragma unroll
            for (int m = 0; m < 4; ++m)
                acc[j][m] = __builtin_amdgcn_mfma_f32_16x16x32_bf16(a[m], bv[j], acc[j][m], 0, 0, 0);
    }
}

template<int NJ>
__device__ __forceinline__ void cq2_store(const unsigned short* __restrict__ s1t,
                                          const unsigned short* __restrict__ xrows,
                                          unsigned short* __restrict__ dst,  // buf + 224
                                          int J0, int kg, int lrow) {
    f32x4 acc[NJ][4];
    cq2_regs<NJ>(s1t, xrows, acc, J0, kg, lrow);
#pragma unroll
    for (int j = 0; j < NJ; ++j) {
        int col = (J0 + j) * 16 + lrow;
#pragma unroll
        for (int m = 0; m < 4; ++m)
#pragma unroll
            for (int r = 0; r < 4; ++r)
                dst[(m * 16 + kg * 4 + r) * BUFP + col] = f2bf(acc[j][m][r]);
    }
}

template<int NJ>
__device__ __forceinline__ void mul_scatter(unsigned short* __restrict__ buf,  // S_A base
                                            f32x4 (&acc)[NJ][4], int J0, int kg, int lrow) {
#pragma unroll
    for (int j = 0; j < NJ; ++j) {
        int col = (J0 + j) * 16 + lrow;
#pragma unroll
        for (int m = 0; m < 4; ++m)
#pragma unroll
            for (int r = 0; r < 4; ++r) {
                int idx = (m * 16 + kg * 4 + r) * BUFP + col;
                buf[idx] = f2bf(bf2f(buf[idx]) * acc[j][m][r]);
            }
    }
}

// proj segment: acc += A(buf seg, K=224) @ B(wpP slot, K=224)
__device__ __forceinline__ void proj_seg(f32x4 (&acc)[4],
                                         const unsigned short* __restrict__ Aseg,
                                         const unsigned short* __restrict__ Bslot,
                                         int kg, int lrow) {
    bf16x8 bv[7];
#pragma unroll
    for (int kc = 0; kc < 7; ++kc)
        bv[kc] = *(const bf16x8*)(Bslot + kg * 8 + kc * 32);
#pragma unroll
    for (int kc = 0; kc < 7; ++kc) {
#pragma unroll
        for (int m = 0; m < 4; ++m) {
            bf16x8 af = *(const bf16x8*)(Aseg + (m * 16 + lrow) * BUFP + kg * 8 + kc * 32);
            acc[m] = __builtin_amdgcn_mfma_f32_16x16x32_bf16(af, bv[kc], acc[m], 0, 0, 0);
        }
    }
}

// ---- k_tail: split-K slot fusion, 64-row tiles, XCD-aware decode ----------
__global__ __launch_bounds__(512, 4) void k_tail(const unsigned short* __restrict__ s1,
                                                 const unsigned short* __restrict__ xqaT,
                                                 const unsigned short* __restrict__ xcb,
                                                 const unsigned short* __restrict__ wpP,
                                                 const float* __restrict__ bp,
                                                 float* __restrict__ out) {
    int bid = blockIdx.x;
    int xcd = bid & 7, idx = bid >> 3;     // idx < 64
    int b = xcd + 8 * (idx >> 5);
    int c0 = (idx & 31) * 64;
    int tid = threadIdx.x;
    int w = tid >> 6, lane = tid & 63;
    int lrow = lane & 15, kg = lane >> 4;
    __shared__ unsigned short s1t[64 * 136];   // 17.4 KB
    __shared__ unsigned short buf[64 * BUFP];  // 58.4 KB

    for (int i = tid; i < 64 * 16; i += 512) {
        int row = i >> 4, c8 = i & 15;
        *(bf16x8*)(s1t + row * 136 + c8 * 8) =
            *(const bf16x8*)(s1 + ((size_t)(b * Cn + c0 + row)) * Qn + c8 * 8);
    }
    for (int i = tid; i < 64 * 28; i += 512) {   // S_A = x (chunks 25..27 zero)
        int row = i / 28, c8 = i % 28;
        bf16x8 v = bf16x8{0,0,0,0,0,0,0,0};
        if (c8 < 25) v = *(const bf16x8*)(xcb + ((size_t)(b * Cn + c0 + row)) * En + c8 * 8);
        *(bf16x8*)(buf + row * BUFP + c8 * 8) = v;
    }
    __syncthreads();

    const unsigned short* xq_b = xqaT + (size_t)b * XR * Qn;

    // ph1a: c2q -> S_B (14 n-tiles over 8 waves)
    if (w < 6)       cq2_store<2>(s1t, xq_b, buf + 224, 2 * w, kg, lrow);
    else if (w == 6) cq2_store<1>(s1t, xq_b, buf + 224, 12, kg, lrow);
    else             cq2_store<1>(s1t, xq_b, buf + 224, 13, kg, lrow);
    __syncthreads();

    // ph2a: acc += x @ slot0 + c2q @ slot1
    f32x4 acc[4] = {};
    {
        const unsigned short* Bo = wpP + ((size_t)(w * 16 + lrow)) * KP;
        proj_seg(acc, buf,       Bo,                        kg, lrow);
        proj_seg(acc, buf + 224, Bo + (size_t)1 * On * KP,  kg, lrow);
    }

    // ph1b: q2c fragments in regs
    f32x4 aq2[2][4];
    if (w < 6)       cq2_regs<2>(s1t, xq_b + (size_t)224 * Qn, aq2, 2 * w, kg, lrow);
    else if (w == 6) { f32x4 t1[1][4]; cq2_regs<1>(s1t, xq_b + (size_t)224 * Qn, t1, 12, kg, lrow);
                       aq2[0][0]=t1[0][0]; aq2[0][1]=t1[0][1]; aq2[0][2]=t1[0][2]; aq2[0][3]=t1[0][3]; }
    else             { f32x4 t1[1][4]; cq2_regs<1>(s1t, xq_b + (size_t)224 * Qn, t1, 13, kg, lrow);
                       aq2[0][0]=t1[0][0]; aq2[0][1]=t1[0][1]; aq2[0][2]=t1[0][2]; aq2[0][3]=t1[0][3]; }
    __syncthreads();

    // mid: S_B = x * c2q (vectorized, amortized across 512 threads)
    for (int i = tid; i < 64 * 28; i += 512) {
        int row = i / 28, c8 = i % 28;
        unsigned short* fr = buf + row * BUFP;
        bf16x8 x  = *(bf16x8*)(fr + c8 * 8);
        bf16x8 c2 = *(bf16x8*)(fr + 224 + c8 * 8);
        *(bf16x8*)(fr + 224 + c8 * 8) = mul8(x, c2);
    }
    __syncthreads();

    // scatter: S_A = x * q2c (self-located: lane reads+writes same slot)
    if (w < 6)       mul_scatter<2>(buf, aq2, 2 * w, kg, lrow);
    else if (w == 6) { f32x4 t1[1][4]; t1[0][0]=aq2[0][0]; t1[0][1]=aq2[0][1]; t1[0][2]=aq2[0][2]; t1[0][3]=aq2[0][3];
                       mul_scatter<1>(buf, t1, 12, kg, lrow); }
    else             { f32x4 t1[1][4]; t1[0][0]=aq2[0][0]; t1[0][1]=aq2[0][1]; t1[0][2]=aq2[0][2]; t1[0][3]=aq2[0][3];
                       mul_scatter<1>(buf, t1, 13, kg, lrow); }
    __syncthreads();

    // ph2b: acc += (x*q2c) @ slot3 + (x*c2q) @ slot2
    {
        const unsigned short* Bo = wpP + ((size_t)(w * 16 + lrow)) * KP;
        proj_seg(acc, buf,       Bo + (size_t)3 * On * KP, kg, lrow);
        proj_seg(acc, buf + 224, Bo + (size_t)2 * On * KP, kg, lrow);
    }

    int o = w * 16 + lrow;
    float bpv = bp[o];
#pragma unroll
    for (int m = 0; m < 4; ++m)
#pragma unroll
        for (int r = 0; r < 4; ++r)
            out[((size_t)(b * Cn + c0 + m * 16 + kg * 4 + r)) * On + o] = acc[m][r] + bpv;
}

extern "C" void kernel_launch(void* const* d_in, const int* in_sizes, int n_in,
                              void* d_out, int out_size, void* d_ws, size_t ws_size,
                              hipStream_t stream) {
    const float* xc = (const float*)d_in[0];
    const float* xq = (const float*)d_in[1];
    const float* wsim = (const float*)d_in[2];
    const float* wp = (const float*)d_in[3];
    const float* bp = (const float*)d_in[4];
    float* out = (float*)d_out;
    float* ws = (float*)d_ws;

    unsigned short* ET_bf   = (unsigned short*)ws;                 // 4,194,304 bf16
    unsigned short* s1_bf   = (unsigned short*)(ws + 2097152);     // 4,194,304 bf16
    unsigned short* xc_bf   = (unsigned short*)(ws + 4194304);     // 6,553,600 bf16
    unsigned short* xcT_bf  = (unsigned short*)(ws + 7471104);     // 6,815,744 bf16
    unsigned short* yq_bf   = (unsigned short*)(ws + 10878976);    //   409,600 bf16
    unsigned short* xqaT_bf = (unsigned short*)(ws + 11083776);    //   917,504 bf16 [b][448][128]
    unsigned short* wpP_bf  = (unsigned short*)(ws + 11542528);    //   114,688 bf16 [4][128][224]
    float* s_q   = ws + 11599872;   //     2,048 f
    float* cpM   = ws + 11601920;   //    65,536 f
    float* cpS   = ws + 11667456;   //    65,536 f
    // total: 11,732,992 floats = 46.9 MB

    k_prep_all<<<2800, 256, 0, stream>>>(xq, wsim, wp, xc, yq_bf, s_q, wpP_bf, xqaT_bf, xc_bf, xcT_bf);
    k_scores_mfma<<<512, 256, 0, stream>>>(xc_bf, yq_bf, s_q, ET_bf, s1_bf, cpM, cpS);
    k_a_fused<<<832, 256, 0, stream>>>(ET_bf, xcT_bf, cpM, cpS, xqaT_bf);
    k_tail<<<512, 512, 0, stream>>>(s1_bf, xqaT_bf, xc_bf, wpP_bf, bp, out);
}

// Round 14
// 88.733 us; speedup vs baseline: 1.1142x; 1.0256x over previous
//
#include <hip/hip_runtime.h>
#include <hip/hip_bf16.h>

#define Bn 16
#define Cn 2048
#define Qn 128
#define En 200
#define Fn 800
#define On 128
#define EP 208   // padded e-rows for xcT
#define KP 224   // padded per-slot K for wpP (7 x K32)
#define XR 448   // xqaT rows: [0,224) xq^T (+pad), [224,448) a^T (+pad)
#define BUFP 456 // k_tail buf pitch (912B = 57x16B, odd -> conflict-floor reads)

typedef float f32x4 __attribute__((ext_vector_type(4)));
typedef __bf16 bf16x8 __attribute__((ext_vector_type(8)));

__device__ __forceinline__ unsigned short f2bf(float f) {
    union { float f; unsigned u; } v; v.f = f;
    unsigned r = v.u + 0x7FFF + ((v.u >> 16) & 1);
    return (unsigned short)(r >> 16);
}
__device__ __forceinline__ float bf2f(unsigned short h) {
    union { unsigned u; float f; } v; v.u = (unsigned)h << 16;
    return v.f;
}
__device__ __forceinline__ bf16x8 mul8(bf16x8 a, bf16x8 b) {
    bf16x8 o;
#pragma unroll
    for (int k = 0; k < 8; ++k) o[k] = (__bf16)((float)a[k] * (float)b[k]);
    return o;
}
__device__ __forceinline__ bf16x8 scale8(bf16x8 a, float s) {
    bf16x8 o;
#pragma unroll
    for (int k = 0; k < 8; ++k) o[k] = (__bf16)((float)a[k] * s);
    return o;
}

// ---- k_prep_all: {yq+s_q | wpP | xq^T+pads | xc->bf16+xc^T} ---------------
// Transposed outputs now stored as ushort4 (4x wider than R13's scalar u16).
__global__ __launch_bounds__(256) void k_prep_all(const float* __restrict__ xq,
                                                  const float* __restrict__ wsim,
                                                  const float* __restrict__ wp,
                                                  const float* __restrict__ xc,
                                                  unsigned short* __restrict__ yqb,
                                                  float* __restrict__ s_q,
                                                  unsigned short* __restrict__ wpP,
                                                  unsigned short* __restrict__ xqaT,
                                                  unsigned short* __restrict__ xcb,
                                                  unsigned short* __restrict__ xcT) {
    int bx = blockIdx.x;
    if (bx < 512) {
        int wid = (bx * 256 + threadIdx.x) >> 6;
        int lane = threadIdx.x & 63;
        const float* xrow = xq + (size_t)wid * En;
        float s = 0.f;
        for (int e = lane; e < En; e += 64) {
            float x = xrow[e];
            yqb[(size_t)wid * En + e] = f2bf(x * wsim[400 + e] + wsim[e]);
            s += x * wsim[200 + e];
        }
        for (int i = 32; i; i >>= 1) s += __shfl_xor(s, i, 64);
        if (lane == 0) s_q[wid] = s;
    } else if (bx < 624) {
        // wpP[s][o][k] = wp[o][s*200+k] (k<200) else 0 ; 112 blocks
        int gid = (bx - 512) * 256 + threadIdx.x;
        int flat = gid * 4;                       // < 4*128*224 = 114688
        int s = flat / (On * KP);
        int rem = flat % (On * KP);
        int o = rem / KP, k = rem % KP;
        ushort4 ov = {0, 0, 0, 0};
        if (k < 200) {
            float4 v = *(const float4*)(wp + (size_t)o * Fn + s * 200 + k);
            ov.x = f2bf(v.x); ov.y = f2bf(v.y); ov.z = f2bf(v.z); ov.w = f2bf(v.w);
        }
        *(ushort4*)(wpP + flat) = ov;
    } else if (bx < 752) {
        // xqaT rows [0,200) = xq^T ; zero pads [200,224) & [424,448)
        int lb = bx - 624;                 // 128 blocks: (4 et, 2 qt, 16 b)
        int et = lb & 3, qt = (lb >> 2) & 1, b = lb >> 3;
        int e0 = et * 64, q0 = qt * 64;
        int tid = threadIdx.x;
        __shared__ float t[64][65];
        for (int i = tid; i < 64 * 64; i += 256) {
            int qi = i >> 6, ei = i & 63;
            int e = e0 + ei;
            t[qi][ei] = (e < En) ? xq[((size_t)(b * Qn + q0 + qi)) * En + e] : 0.f;
        }
        __syncthreads();
        for (int i = tid; i < 64 * 16; i += 256) {   // ushort4-wide transposed store
            int ei = i >> 4, q4 = (i & 15) * 4;
            int e = e0 + ei;
            if (e < En) {
                ushort4 o;
                o.x = f2bf(t[q4][ei]);     o.y = f2bf(t[q4 + 1][ei]);
                o.z = f2bf(t[q4 + 2][ei]); o.w = f2bf(t[q4 + 3][ei]);
                *(ushort4*)(xqaT + ((size_t)(b * XR + e)) * Qn + q0 + q4) = o;
            }
        }
        if (et == 3) {
            for (int i = tid; i < 24 * 64; i += 256) {
                int e = 200 + (i >> 6), q = q0 + (i & 63);
                xqaT[((size_t)(b * XR + e)) * Qn + q] = 0;
            }
            for (int i = tid; i < 24 * 64; i += 256) {
                int e = 424 + (i >> 6), q = q0 + (i & 63);
                xqaT[((size_t)(b * XR + e)) * Qn + q] = 0;
            }
        }
    } else {
        int lb = bx - 752;                 // 2048 blocks: (32 ct, 4 et, 16 b)
        int ct = lb & 31, et = (lb >> 5) & 3, b = lb >> 7;
        int c0 = ct * 64, e0 = et * 64;
        int tid = threadIdx.x;
        __shared__ float t[64][65];
        for (int i = tid; i < 64 * 64; i += 256) {
            int ci = i >> 6, ei = i & 63;
            int e = e0 + ei;
            t[ci][ei] = (e < En) ? xc[((size_t)(b * Cn + c0 + ci)) * En + e] : 0.f;
        }
        __syncthreads();
        for (int i = tid; i < 64 * 16; i += 256) {
            int ci = i >> 4, g4 = (i & 15) * 4;
            int e = e0 + g4;
            if (e + 3 < En) {
                ushort4 o;
                o.x = f2bf(t[ci][g4]); o.y = f2bf(t[ci][g4 + 1]);
                o.z = f2bf(t[ci][g4 + 2]); o.w = f2bf(t[ci][g4 + 3]);
                *(ushort4*)(xcb + ((size_t)(b * Cn + c0 + ci)) * En + e) = o;
            }
        }
        for (int i = tid; i < 64 * 16; i += 256) {   // ushort4-wide transposed store
            int ei = i >> 4, c4 = (i & 15) * 4;
            int e = e0 + ei;
            if (e < EP) {
                ushort4 o;
                o.x = f2bf(t[c4][ei]);     o.y = f2bf(t[c4 + 1][ei]);
                o.z = f2bf(t[c4 + 2][ei]); o.w = f2bf(t[c4 + 3][ei]);
                *(ushort4*)(xcT + ((size_t)(b * EP + e)) * Cn + c0 + c4) = o;
            }
        }
    }
}

// ---- k_scores_mfma: scores GEMM + fused row softmax (s1) + block-local ----
// 1D grid (512) with XCD-aware decode: all 32 c-blocks of batch b share an XCD
__global__ __launch_bounds__(256) void k_scores_mfma(const unsigned short* __restrict__ xcb,
                                                     const unsigned short* __restrict__ yqb,
                                                     const float* __restrict__ s_q,
                                                     unsigned short* __restrict__ ET,
                                                     unsigned short* __restrict__ s1,
                                                     float* __restrict__ cpM,
                                                     float* __restrict__ cpS) {
    int bid = blockIdx.x;
    int xcd = bid & 7, idx = bid >> 3;     // idx < 64
    int b = xcd + 8 * (idx >> 5);
    int blk = idx & 31;
    int c0 = blk * 64;
    int w = threadIdx.x >> 6, lane = threadIdx.x & 63;
    int lrow = lane & 15, kg = lane >> 4;
    __shared__ float colm4[4][128];
    __shared__ float cols4[4][128];
    const unsigned short* Ab = xcb + ((size_t)(b * Cn + c0 + w * 16 + lrow)) * En + kg * 8;
    const unsigned short* Bb = yqb + ((size_t)(b * Qn + lrow)) * En + kg * 8;
    f32x4 acc[8] = {};
#pragma unroll
    for (int kc = 0; kc < 7; ++kc) {
        bool valid = (kc < 6) || (kg == 0);
        bf16x8 af = bf16x8{0,0,0,0,0,0,0,0};
        if (valid) af = *(const bf16x8*)(Ab + kc * 32);
        bf16x8 bfr[8];
#pragma unroll
        for (int j = 0; j < 8; ++j) {
            bfr[j] = bf16x8{0,0,0,0,0,0,0,0};
            if (valid) bfr[j] = *(const bf16x8*)(Bb + (size_t)j * 16 * En + kc * 32);
        }
#pragma unroll
        for (int j = 0; j < 8; ++j)
            acc[j] = __builtin_amdgcn_mfma_f32_16x16x32_bf16(af, bfr[j], acc[j], 0, 0, 0);
    }
#pragma unroll
    for (int j = 0; j < 8; ++j) {
        float sq = s_q[b * Qn + j * 16 + lrow];
#pragma unroll
        for (int r = 0; r < 4; ++r) acc[j][r] += sq;
    }
    float lm[8], ls[8];
#pragma unroll
    for (int j = 0; j < 8; ++j) {
        float m = fmaxf(fmaxf(acc[j][0], acc[j][1]), fmaxf(acc[j][2], acc[j][3]));
        m = fmaxf(m, __shfl_xor(m, 16, 64));
        m = fmaxf(m, __shfl_xor(m, 32, 64));
        lm[j] = m;
        float s = __expf(acc[j][0] - m) + __expf(acc[j][1] - m)
                + __expf(acc[j][2] - m) + __expf(acc[j][3] - m);
        s += __shfl_xor(s, 16, 64);
        s += __shfl_xor(s, 32, 64);
        ls[j] = s;
    }
    if (kg == 0) {
#pragma unroll
        for (int j = 0; j < 8; ++j) {
            colm4[w][j * 16 + lrow] = lm[j];
            cols4[w][j * 16 + lrow] = ls[j];
        }
    }
    __syncthreads();
    float mb[8];
#pragma unroll
    for (int j = 0; j < 8; ++j) {
        int q = j * 16 + lrow;
        float m = fmaxf(fmaxf(colm4[0][q], colm4[1][q]), fmaxf(colm4[2][q], colm4[3][q]));
        mb[j] = m;
        if (w == 0 && kg == 0) {
            float sb = cols4[0][q] * __expf(colm4[0][q] - m)
                     + cols4[1][q] * __expf(colm4[1][q] - m)
                     + cols4[2][q] * __expf(colm4[2][q] - m)
                     + cols4[3][q] * __expf(colm4[3][q] - m);
            cpM[(b * 32 + blk) * 128 + q] = m;
            cpS[(b * 32 + blk) * 128 + q] = sb;
        }
    }
#pragma unroll
    for (int j = 0; j < 8; ++j) {
        int q = j * 16 + lrow;
        ushort4 o;
        o.x = f2bf(__expf(acc[j][0] - mb[j]));
        o.y = f2bf(__expf(acc[j][1] - mb[j]));
        o.z = f2bf(__expf(acc[j][2] - mb[j]));
        o.w = f2bf(__expf(acc[j][3] - mb[j]));
        *(ushort4*)(ET + ((size_t)(b * Qn + q)) * Cn + c0 + w * 16 + kg * 4) = o;
    }
    size_t rowbase = (size_t)(b * Cn + c0 + w * 16 + kg * 4);
#pragma unroll
    for (int r = 0; r < 4; ++r) {
        float m = acc[0][r];
#pragma unroll
        for (int j = 1; j < 8; ++j) m = fmaxf(m, acc[j][r]);
        for (int d = 1; d < 16; d <<= 1) m = fmaxf(m, __shfl_xor(m, d, 64));
        float ssum = 0.f;
        float e[8];
#pragma unroll
        for (int j = 0; j < 8; ++j) {
            e[j] = __expf(acc[j][r] - m);
            ssum += e[j];
        }
        for (int d = 1; d < 16; d <<= 1) ssum += __shfl_xor(ssum, d, 64);
        float si = 1.f / ssum;
#pragma unroll
        for (int j = 0; j < 8; ++j)
            s1[(rowbase + r) * Qn + j * 16 + lrow] = f2bf(e[j] * si);
    }
}

// ---- k_a_fused: a^T = xcT @ (ET*corr)^T; XCD-aware decode -----------------
__global__ __launch_bounds__(256) void k_a_fused(const unsigned short* __restrict__ ET,
                                                 const unsigned short* __restrict__ xcT,
                                                 const float* __restrict__ cpM,
                                                 const float* __restrict__ cpS,
                                                 unsigned short* __restrict__ xqaT) {
    int bid = blockIdx.x;                 // 832 blocks
    int xcd = bid & 7, idx = bid >> 3;    // idx < 104
    int b = xcd + 8 * (idx / 52);
    int r52 = idx % 52;
    int mt = r52 % 13, qp = r52 / 13;
    int tid = threadIdx.x;
    int w = tid >> 6, lane = tid & 63;
    int lrow = lane & 15, kg = lane >> 4;
    __shared__ float colMs[128], colSis[128];
    __shared__ float red[4][2][16][16];
    if (tid < 128) {
        int q = tid;
        float m = -1e30f;
        for (int k = 0; k < 32; k++) m = fmaxf(m, cpM[(b * 32 + k) * 128 + q]);
        float s = 0.f;
        for (int k = 0; k < 32; k++) s += cpS[(b * 32 + k) * 128 + q] * __expf(cpM[(b * 32 + k) * 128 + q] - m);
        colMs[q] = m;
        colSis[q] = 1.f / s;
    }
    __syncthreads();
    int q0 = qp * 16 + lrow, q1 = q0 + 64;
    float corr0[8], corr1[8];
#pragma unroll
    for (int i = 0; i < 8; ++i) {
        int cb = w * 8 + i;
        corr0[i] = __expf(cpM[(b * 32 + cb) * 128 + q0] - colMs[q0]) * colSis[q0];
        corr1[i] = __expf(cpM[(b * 32 + cb) * 128 + q1] - colMs[q1]) * colSis[q1];
    }
    const unsigned short* Ab = xcT + ((size_t)(b * EP + mt * 16 + lrow)) * Cn + w * 512 + kg * 8;
    const unsigned short* B0 = ET + ((size_t)(b * Qn + q0)) * Cn + w * 512 + kg * 8;
    const unsigned short* B1 = ET + ((size_t)(b * Qn + q1)) * Cn + w * 512 + kg * 8;
    f32x4 acc0 = {}, acc1 = {};
#pragma unroll
    for (int kb = 0; kb < 4; ++kb) {
        bf16x8 af[4], bv0[4], bv1[4];
#pragma unroll
        for (int k4 = 0; k4 < 4; ++k4) {
            af[k4]  = *(const bf16x8*)(Ab + (kb * 4 + k4) * 32);
            bv0[k4] = *(const bf16x8*)(B0 + (kb * 4 + k4) * 32);
            bv1[k4] = *(const bf16x8*)(B1 + (kb * 4 + k4) * 32);
        }
#pragma unroll
        for (int k4 = 0; k4 < 4; ++k4) {
            bf16x8 s0 = scale8(bv0[k4], corr0[kb * 2 + (k4 >> 1)]);
            bf16x8 s1v = scale8(bv1[k4], corr1[kb * 2 + (k4 >> 1)]);
            acc0 = __builtin_amdgcn_mfma_f32_16x16x32_bf16(af[k4], s0, acc0, 0, 0, 0);
            acc1 = __builtin_amdgcn_mfma_f32_16x16x32_bf16(af[k4], s1v, acc1, 0, 0, 0);
        }
    }
#pragma unroll
    for (int r = 0; r < 4; ++r) {
        red[w][0][kg * 4 + r][lrow] = acc0[r];
        red[w][1][kg * 4 + r][lrow] = acc1[r];
    }
    __syncthreads();
#pragma unroll
    for (int t = 0; t < 2; ++t) {
        int idx2 = tid + t * 256;
        int half = idx2 >> 8, rem = idx2 & 255;
        int row = rem >> 4, col = rem & 15;
        float s = red[0][half][row][col] + red[1][half][row][col]
                + red[2][half][row][col] + red[3][half][row][col];
        int e = mt * 16 + row;
        int q = qp * 16 + half * 64 + col;
        if (e < En)
            xqaT[((size_t)(b * XR + 224 + e)) * Qn + q] = f2bf(s);
    }
}

// ---- cq helpers: NJ n-tiles x 4 m-tiles of s1t @ xrows --------------------
template<int NJ>
__device__ __forceinline__ void cq2_regs(const unsigned short* __restrict__ s1t,
                                         const unsigned short* __restrict__ xrows,
                                         f32x4 (&acc)[NJ][4], int J0, int kg, int lrow) {
#pragma unroll
    for (int j = 0; j < NJ; ++j)
#pragma unroll
        for (int m = 0; m < 4; ++m) acc[j][m] = f32x4{0.f, 0.f, 0.f, 0.f};
#pragma unroll
    for (int kc = 0; kc < 4; ++kc) {
        bf16x8 a[4];
#pragma unroll
        for (int m = 0; m < 4; ++m)
            a[m] = *(const bf16x8*)(s1t + (m * 16 + lrow) * 136 + kg * 8 + kc * 32);
        bf16x8 bv[NJ];
#pragma unroll
        for (int j = 0; j < NJ; ++j)
            bv[j] = *(const bf16x8*)(xrows + ((size_t)((J0 + j) * 16 + lrow)) * Qn + kg * 8 + kc * 32);
#pragma unroll
        for (int j = 0; j < NJ; ++j)
#pragma unroll
            for (int m = 0; m < 4; ++m)
                acc[j][m] = __builtin_amdgcn_mfma_f32_16x16x32_bf16(a[m], bv[j], acc[j][m], 0, 0, 0);
    }
}

template<int NJ>
__device__ __forceinline__ void cq2_store(const unsigned short* __restrict__ s1t,
                                          const unsigned short* __restrict__ xrows,
                                          unsigned short* __restrict__ dst,  // buf + 224
                                          int J0, int kg, int lrow) {
    f32x4 acc[NJ][4];
    cq2_regs<NJ>(s1t, xrows, acc, J0, kg, lrow);
#pragma unroll
    for (int j = 0; j < NJ; ++j) {
        int col = (J0 + j) * 16 + lrow;
#pragma unroll
        for (int m = 0; m < 4; ++m)
#pragma unroll
            for (int r = 0; r < 4; ++r)
                dst[(m * 16 + kg * 4 + r) * BUFP + col] = f2bf(acc[j][m][r]);
    }
}

template<int NJ>
__device__ __forceinline__ void mul_scatter(unsigned short* __restrict__ buf,  // S_A base
                                            f32x4 (&acc)[NJ][4], int J0, int kg, int lrow) {
#pragma unroll
    for (int j = 0; j < NJ; ++j) {
        int col = (J0 + j) * 16 + lrow;
#pragma unroll
        for (int m = 0; m < 4; ++m)
#pragma unroll
            for (int r = 0; r < 4; ++r) {
                int idx = (m * 16 + kg * 4 + r) * BUFP + col;
                buf[idx] = f2bf(bf2f(buf[idx]) * acc[j][m][r]);
            }
    }
}

// proj segment: acc += A(buf seg, K=224) @ B(wpP slot, K=224)
__device__ __forceinline__ void proj_seg(f32x4 (&acc)[4],
                                         const unsigned short* __restrict__ Aseg,
                                         const unsigned short* __restrict__ Bslot,
                                         int kg, int lrow) {
    bf16x8 bv[7];
#pragma unroll
    for (int kc = 0; kc < 7; ++kc)
        bv[kc] = *(const bf16x8*)(Bslot + kg * 8 + kc * 32);
#pragma unroll
    for (int kc = 0; kc < 7; ++kc) {
#pragma unroll
        for (int m = 0; m < 4; ++m) {
            bf16x8 af = *(const bf16x8*)(Aseg + (m * 16 + lrow) * BUFP + kg * 8 + kc * 32);
            acc[m] = __builtin_amdgcn_mfma_f32_16x16x32_bf16(af, bv[kc], acc[m], 0, 0, 0);
        }
    }
}

// ---- k_tail: split-K slot fusion, 64-row tiles, XCD-aware decode ----------
__global__ __launch_bounds__(512, 4) void k_tail(const unsigned short* __restrict__ s1,
                                                 const unsigned short* __restrict__ xqaT,
                                                 const unsigned short* __restrict__ xcb,
                                                 const unsigned short* __restrict__ wpP,
                                                 const float* __restrict__ bp,
                                                 float* __restrict__ out) {
    int bid = blockIdx.x;
    int xcd = bid & 7, idx = bid >> 3;     // idx < 64
    int b = xcd + 8 * (idx >> 5);
    int c0 = (idx & 31) * 64;
    int tid = threadIdx.x;
    int w = tid >> 6, lane = tid & 63;
    int lrow = lane & 15, kg = lane >> 4;
    __shared__ unsigned short s1t[64 * 136];   // 17.4 KB
    __shared__ unsigned short buf[64 * BUFP];  // 58.4 KB

    for (int i = tid; i < 64 * 16; i += 512) {
        int row = i >> 4, c8 = i & 15;
        *(bf16x8*)(s1t + row * 136 + c8 * 8) =
            *(const bf16x8*)(s1 + ((size_t)(b * Cn + c0 + row)) * Qn + c8 * 8);
    }
    for (int i = tid; i < 64 * 28; i += 512) {   // S_A = x (chunks 25..27 zero)
        int row = i / 28, c8 = i % 28;
        bf16x8 v = bf16x8{0,0,0,0,0,0,0,0};
        if (c8 < 25) v = *(const bf16x8*)(xcb + ((size_t)(b * Cn + c0 + row)) * En + c8 * 8);
        *(bf16x8*)(buf + row * BUFP + c8 * 8) = v;
    }
    __syncthreads();

    const unsigned short* xq_b = xqaT + (size_t)b * XR * Qn;

    // ph1a: c2q -> S_B (14 n-tiles over 8 waves)
    if (w < 6)       cq2_store<2>(s1t, xq_b, buf + 224, 2 * w, kg, lrow);
    else if (w == 6) cq2_store<1>(s1t, xq_b, buf + 224, 12, kg, lrow);
    else             cq2_store<1>(s1t, xq_b, buf + 224, 13, kg, lrow);
    __syncthreads();

    // ph2a: acc += x @ slot0 + c2q @ slot1
    f32x4 acc[4] = {};
    {
        const unsigned short* Bo = wpP + ((size_t)(w * 16 + lrow)) * KP;
        proj_seg(acc, buf,       Bo,                        kg, lrow);
        proj_seg(acc, buf + 224, Bo + (size_t)1 * On * KP,  kg, lrow);
    }

    // ph1b: q2c fragments in regs
    f32x4 aq2[2][4];
    if (w < 6)       cq2_regs<2>(s1t, xq_b + (size_t)224 * Qn, aq2, 2 * w, kg, lrow);
    else if (w == 6) { f32x4 t1[1][4]; cq2_regs<1>(s1t, xq_b + (size_t)224 * Qn, t1, 12, kg, lrow);
                       aq2[0][0]=t1[0][0]; aq2[0][1]=t1[0][1]; aq2[0][2]=t1[0][2]; aq2[0][3]=t1[0][3]; }
    else             { f32x4 t1[1][4]; cq2_regs<1>(s1t, xq_b + (size_t)224 * Qn, t1, 13, kg, lrow);
                       aq2[0][0]=t1[0][0]; aq2[0][1]=t1[0][1]; aq2[0][2]=t1[0][2]; aq2[0][3]=t1[0][3]; }
    __syncthreads();

    // mid: S_B = x * c2q (vectorized, amortized across 512 threads)
    for (int i = tid; i < 64 * 28; i += 512) {
        int row = i / 28, c8 = i % 28;
        unsigned short* fr = buf + row * BUFP;
        bf16x8 x  = *(bf16x8*)(fr + c8 * 8);
        bf16x8 c2 = *(bf16x8*)(fr + 224 + c8 * 8);
        *(bf16x8*)(fr + 224 + c8 * 8) = mul8(x, c2);
    }
    __syncthreads();

    // scatter: S_A = x * q2c (self-located: lane reads+writes same slot)
    if (w < 6)       mul_scatter<2>(buf, aq2, 2 * w, kg, lrow);
    else if (w == 6) { f32x4 t1[1][4]; t1[0][0]=aq2[0][0]; t1[0][1]=aq2[0][1]; t1[0][2]=aq2[0][2]; t1[0][3]=aq2[0][3];
                       mul_scatter<1>(buf, t1, 12, kg, lrow); }
    else             { f32x4 t1[1][4]; t1[0][0]=aq2[0][0]; t1[0][1]=aq2[0][1]; t1[0][2]=aq2[0][2]; t1[0][3]=aq2[0][3];
                       mul_scatter<1>(buf, t1, 13, kg, lrow); }
    __syncthreads();

    // ph2b: acc += (x*q2c) @ slot3 + (x*c2q) @ slot2
    {
        const unsigned short* Bo = wpP + ((size_t)(w * 16 + lrow)) * KP;
        proj_seg(acc, buf,       Bo + (size_t)3 * On * KP, kg, lrow);
        proj_seg(acc, buf + 224, Bo + (size_t)2 * On * KP, kg, lrow);
    }

    int o = w * 16 + lrow;
    float bpv = bp[o];
#pragma unroll
    for (int m = 0; m < 4; ++m)
#pragma unroll
        for (int r = 0; r < 4; ++r)
            out[((size_t)(b * Cn + c0 + m * 16 + kg * 4 + r)) * On + o] = acc[m][r] + bpv;
}

extern "C" void kernel_launch(void* const* d_in, const int* in_sizes, int n_in,
                              void* d_out, int out_size, void* d_ws, size_t ws_size,
                              hipStream_t stream) {
    const float* xc = (const float*)d_in[0];
    const float* xq = (const float*)d_in[1];
    const float* wsim = (const float*)d_in[2];
    const float* wp = (const float*)d_in[3];
    const float* bp = (const float*)d_in[4];
    float* out = (float*)d_out;
    float* ws = (float*)d_ws;

    unsigned short* ET_bf   = (unsigned short*)ws;                 // 4,194,304 bf16
    unsigned short* s1_bf   = (unsigned short*)(ws + 2097152);     // 4,194,304 bf16
    unsigned short* xc_bf   = (unsigned short*)(ws + 4194304);     // 6,553,600 bf16
    unsigned short* xcT_bf  = (unsigned short*)(ws + 7471104);     // 6,815,744 bf16
    unsigned short* yq_bf   = (unsigned short*)(ws + 10878976);    //   409,600 bf16
    unsigned short* xqaT_bf = (unsigned short*)(ws + 11083776);    //   917,504 bf16 [b][448][128]
    unsigned short* wpP_bf  = (unsigned short*)(ws + 11542528);    //   114,688 bf16 [4][128][224]
    float* s_q   = ws + 11599872;   //     2,048 f
    float* cpM   = ws + 11601920;   //    65,536 f
    float* cpS   = ws + 11667456;   //    65,536 f
    // total: 11,732,992 floats = 46.9 MB

    k_prep_all<<<2800, 256, 0, stream>>>(xq, wsim, wp, xc, yq_bf, s_q, wpP_bf, xqaT_bf, xc_bf, xcT_bf);
    k_scores_mfma<<<512, 256, 0, stream>>>(xc_bf, yq_bf, s_q, ET_bf, s1_bf, cpM, cpS);
    k_a_fused<<<832, 256, 0, stream>>>(ET_bf, xcT_bf, cpM, cpS, xqaT_bf);
    k_tail<<<512, 512, 0, stream>>>(s1_bf, xqaT_bf, xc_bf, wpP_bf, bp, out);
}